// Round 2
// baseline (213.005 us; speedup 1.0000x reference)
//
#include <hip/hip_runtime.h>
#include <math.h>

#define NOBS 7
#define TWO_PI_F 6.283185307179586f

// Bit layout of the 10-bit amplitude index (wire w -> bit 9-w):
//   bits 0..3  = register-local per lane:  b0=wire9(anc1) b1=wire8(anc0) b2=wire7 b3=wire6
//   bits 4..9  = lane bits:                lane bit (5-w) = wire w, for w=0..5
// Lane `lane` register r holds amplitude index  idx = lane*16 + r.

constexpr int REG_MASK(int w)  { return w==6 ? 8 : w==7 ? 4 : w==8 ? 2 : w==9 ? 1 : 0; }
constexpr int LANE_MASK(int w) { return w<=5 ? (1 << (5-w)) : 0; }

// ---------------- in-register gate helpers ----------------

// RY on wire W; angles per ancilla j=r&3 from float4 tables at entry aidx; sign sg.
template<int W>
__device__ __forceinline__ void ry_gate(float* vr, float* vi, int lane,
                                        const float4* ctab, const float4* stab,
                                        int aidx, float sg)
{
  float4 C = ctab[aidx];
  float4 S = stab[aidx];
  float c[4] = {C.x, C.y, C.z, C.w};
  float s[4] = {sg*S.x, sg*S.y, sg*S.z, sg*S.w};
  if constexpr (REG_MASK(W) != 0) {
    constexpr int m = REG_MASK(W);
#pragma unroll
    for (int r = 0; r < 16; ++r) {
      if (r & m) continue;
      const int r1 = r | m, j = r & 3;
      float a0 = vr[r], a1 = vr[r1];
      vr[r]  = c[j]*a0 - s[j]*a1;
      vr[r1] = s[j]*a0 + c[j]*a1;
      float b0 = vi[r], b1 = vi[r1];
      vi[r]  = c[j]*b0 - s[j]*b1;
      vi[r1] = s[j]*b0 + c[j]*b1;
    }
  } else {
    constexpr int LM = LANE_MASK(W);
    const float lsign = (lane & LM) ? 1.f : -1.f;
    float ls[4] = {lsign*s[0], lsign*s[1], lsign*s[2], lsign*s[3]};
#pragma unroll
    for (int r = 0; r < 16; ++r) {
      const int j = r & 3;
      float pr = __shfl_xor(vr[r], LM, 64);
      float pi = __shfl_xor(vi[r], LM, 64);
      vr[r] = c[j]*vr[r] + ls[j]*pr;   // low lane: c*a0 - s*a1 ; high: c*a1 + s*a0
      vi[r] = c[j]*vi[r] + ls[j]*pi;
    }
  }
}

// CRX(control WC, target WT): on control=1 subspace, for each pair across target bit:
//   new_re = c*self_re + s*partner_im ;  new_im = c*self_im - s*partner_re   (symmetric)
template<int WC, int WT>
__device__ __forceinline__ void crx_gate(float* vr, float* vi, int lane,
                                         const float4* ctab, const float4* stab,
                                         int aidx, float sg)
{
  float4 C = ctab[aidx];
  float4 S = stab[aidx];
  float c[4] = {C.x, C.y, C.z, C.w};
  float s[4] = {sg*S.x, sg*S.y, sg*S.z, sg*S.w};
  constexpr int MC = REG_MASK(WC), LC = LANE_MASK(WC);
  constexpr int MT = REG_MASK(WT), LT = LANE_MASK(WT);
  if constexpr (MC != 0 && MT != 0) {
#pragma unroll
    for (int r = 0; r < 16; ++r) {
      if (!(r & MC) || (r & MT)) continue;
      const int r1 = r | MT, j = r & 3;
      float xr = vr[r],  xi = vi[r],  yr = vr[r1], yi = vi[r1];
      vr[r]  = c[j]*xr + s[j]*yi;  vi[r]  = c[j]*xi - s[j]*yr;
      vr[r1] = c[j]*yr + s[j]*xi;  vi[r1] = c[j]*yi - s[j]*xr;
    }
  } else if constexpr (MC != 0) {  // control register-local, target wave bit
#pragma unroll
    for (int r = 0; r < 16; ++r) {
      if (!(r & MC)) continue;
      const int j = r & 3;
      float pr = __shfl_xor(vr[r], LT, 64);
      float pi = __shfl_xor(vi[r], LT, 64);
      vr[r] = c[j]*vr[r] + s[j]*pi;
      vi[r] = c[j]*vi[r] - s[j]*pr;
    }
  } else if constexpr (MT != 0) {  // control wave bit, target register-local
    const bool act = (lane & LC) != 0;
#pragma unroll
    for (int r = 0; r < 16; ++r) {
      if (r & MT) continue;
      const int r1 = r | MT, j = r & 3;
      float xr = vr[r],  xi = vi[r],  yr = vr[r1], yi = vi[r1];
      float nxr = c[j]*xr + s[j]*yi, nxi = c[j]*xi - s[j]*yr;
      float nyr = c[j]*yr + s[j]*xi, nyi = c[j]*yi - s[j]*xr;
      vr[r]  = act ? nxr : xr;  vi[r]  = act ? nxi : xi;
      vr[r1] = act ? nyr : yr;  vi[r1] = act ? nyi : yi;
    }
  } else {  // both wave bits
    const bool act = (lane & LC) != 0;
#pragma unroll
    for (int r = 0; r < 16; ++r) {
      const int j = r & 3;
      float pr = __shfl_xor(vr[r], LT, 64);
      float pi = __shfl_xor(vi[r], LT, 64);
      float nr = c[j]*vr[r] + s[j]*pi;
      float ni = c[j]*vi[r] - s[j]*pr;
      vr[r] = act ? nr : vr[r];
      vi[r] = act ? ni : vi[r];
    }
  }
}

// general complex 1q gate on register bit M (prepare on ancilla wires)
template<int M>
__device__ __forceinline__ void g1q(float* vr, float* vi,
    float u00r, float u00i, float u01r, float u01i,
    float u10r, float u10i, float u11r, float u11i)
{
#pragma unroll
  for (int r = 0; r < 16; ++r) {
    if (r & M) continue;
    const int r1 = r | M;
    float ar = vr[r], ai = vi[r], br = vr[r1], bi = vi[r1];
    vr[r]  = u00r*ar - u00i*ai + u01r*br - u01i*bi;
    vi[r]  = u00r*ai + u00i*ar + u01r*bi + u01i*br;
    vr[r1] = u10r*ar - u10i*ai + u11r*br - u11i*bi;
    vi[r1] = u10r*ai + u10i*ar + u11r*bi + u11i*br;
  }
}

// CNOT control wire8 (bit1), target wire9 (bit0): swap r<->r|1 where bit1 set
__device__ __forceinline__ void cnot_anc(float* vr, float* vi)
{
#pragma unroll
  for (int r = 2; r < 16; r += 4) {
    float tr = vr[r], ti = vi[r];
    vr[r] = vr[r+1]; vi[r] = vi[r+1];
    vr[r+1] = tr;    vi[r+1] = ti;
  }
}

__device__ __forceinline__ void pcphase(float* vr, float* vi, float cph, float sph)
{
#pragma unroll
  for (int r = 0; r < 16; ++r) {
    const float sp = ((r & 3) == 0) ? sph : -sph;
    float ar = vr[r], ai = vi[r];
    vr[r] = cph*ar - sp*ai;
    vi[r] = sp*ar + cph*ai;
  }
}

// ---------------- sim14 layers (32 gates each) ----------------

__device__ __forceinline__ void sim14_fwd(float* vr, float* vi, int lane,
    const float4* ct, const float4* st, int off, float sg)
{
  ry_gate<0>(vr,vi,lane,ct,st,off+0,sg);  ry_gate<1>(vr,vi,lane,ct,st,off+1,sg);
  ry_gate<2>(vr,vi,lane,ct,st,off+2,sg);  ry_gate<3>(vr,vi,lane,ct,st,off+3,sg);
  ry_gate<4>(vr,vi,lane,ct,st,off+4,sg);  ry_gate<5>(vr,vi,lane,ct,st,off+5,sg);
  ry_gate<6>(vr,vi,lane,ct,st,off+6,sg);  ry_gate<7>(vr,vi,lane,ct,st,off+7,sg);
  crx_gate<7,0>(vr,vi,lane,ct,st,off+8,sg);  crx_gate<6,7>(vr,vi,lane,ct,st,off+9,sg);
  crx_gate<5,6>(vr,vi,lane,ct,st,off+10,sg); crx_gate<4,5>(vr,vi,lane,ct,st,off+11,sg);
  crx_gate<3,4>(vr,vi,lane,ct,st,off+12,sg); crx_gate<2,3>(vr,vi,lane,ct,st,off+13,sg);
  crx_gate<1,2>(vr,vi,lane,ct,st,off+14,sg); crx_gate<0,1>(vr,vi,lane,ct,st,off+15,sg);
  ry_gate<0>(vr,vi,lane,ct,st,off+16,sg); ry_gate<1>(vr,vi,lane,ct,st,off+17,sg);
  ry_gate<2>(vr,vi,lane,ct,st,off+18,sg); ry_gate<3>(vr,vi,lane,ct,st,off+19,sg);
  ry_gate<4>(vr,vi,lane,ct,st,off+20,sg); ry_gate<5>(vr,vi,lane,ct,st,off+21,sg);
  ry_gate<6>(vr,vi,lane,ct,st,off+22,sg); ry_gate<7>(vr,vi,lane,ct,st,off+23,sg);
  crx_gate<7,6>(vr,vi,lane,ct,st,off+24,sg); crx_gate<0,7>(vr,vi,lane,ct,st,off+25,sg);
  crx_gate<1,0>(vr,vi,lane,ct,st,off+26,sg); crx_gate<2,1>(vr,vi,lane,ct,st,off+27,sg);
  crx_gate<3,2>(vr,vi,lane,ct,st,off+28,sg); crx_gate<4,3>(vr,vi,lane,ct,st,off+29,sg);
  crx_gate<5,4>(vr,vi,lane,ct,st,off+30,sg); crx_gate<6,5>(vr,vi,lane,ct,st,off+31,sg);
}

__device__ __forceinline__ void sim14_adj(float* vr, float* vi, int lane,
    const float4* ct, const float4* st, int off)
{
  const float sg = -1.f;
  crx_gate<6,5>(vr,vi,lane,ct,st,off+31,sg); crx_gate<5,4>(vr,vi,lane,ct,st,off+30,sg);
  crx_gate<4,3>(vr,vi,lane,ct,st,off+29,sg); crx_gate<3,2>(vr,vi,lane,ct,st,off+28,sg);
  crx_gate<2,1>(vr,vi,lane,ct,st,off+27,sg); crx_gate<1,0>(vr,vi,lane,ct,st,off+26,sg);
  crx_gate<0,7>(vr,vi,lane,ct,st,off+25,sg); crx_gate<7,6>(vr,vi,lane,ct,st,off+24,sg);
  ry_gate<7>(vr,vi,lane,ct,st,off+23,sg); ry_gate<6>(vr,vi,lane,ct,st,off+22,sg);
  ry_gate<5>(vr,vi,lane,ct,st,off+21,sg); ry_gate<4>(vr,vi,lane,ct,st,off+20,sg);
  ry_gate<3>(vr,vi,lane,ct,st,off+19,sg); ry_gate<2>(vr,vi,lane,ct,st,off+18,sg);
  ry_gate<1>(vr,vi,lane,ct,st,off+17,sg); ry_gate<0>(vr,vi,lane,ct,st,off+16,sg);
  crx_gate<0,1>(vr,vi,lane,ct,st,off+15,sg); crx_gate<1,2>(vr,vi,lane,ct,st,off+14,sg);
  crx_gate<2,3>(vr,vi,lane,ct,st,off+13,sg); crx_gate<3,4>(vr,vi,lane,ct,st,off+12,sg);
  crx_gate<4,5>(vr,vi,lane,ct,st,off+11,sg); crx_gate<5,6>(vr,vi,lane,ct,st,off+10,sg);
  crx_gate<6,7>(vr,vi,lane,ct,st,off+9,sg);  crx_gate<7,0>(vr,vi,lane,ct,st,off+8,sg);
  ry_gate<7>(vr,vi,lane,ct,st,off+7,sg); ry_gate<6>(vr,vi,lane,ct,st,off+6,sg);
  ry_gate<5>(vr,vi,lane,ct,st,off+5,sg); ry_gate<4>(vr,vi,lane,ct,st,off+4,sg);
  ry_gate<3>(vr,vi,lane,ct,st,off+3,sg); ry_gate<2>(vr,vi,lane,ct,st,off+2,sg);
  ry_gate<1>(vr,vi,lane,ct,st,off+1,sg); ry_gate<0>(vr,vi,lane,ct,st,off+0,sg);
}

// ---------------- main kernel: one wave (64 threads) per batch element ----------------

__global__ __launch_bounds__(64) void qsvt_kernel(
    const float* __restrict__ z_t, const float* __restrict__ t,
    const float* __restrict__ te_w1, const float* __restrict__ te_b1,
    const float* __restrict__ te_w2, const float* __restrict__ te_b2,
    const float* __restrict__ ip_w1, const float* __restrict__ ip_b1,
    const float* __restrict__ ip_w2, const float* __restrict__ ip_b2,
    const float* __restrict__ prep_p, const float* __restrict__ sig,
    const float* __restrict__ qff, const float* __restrict__ A_obs,
    const float* __restrict__ B_obs, const float* __restrict__ D_obs,
    const float* __restrict__ head_w, const float* __restrict__ head_b,
    float* __restrict__ out)
{
  __shared__ __align__(16) float emb[128];
  __shared__ __align__(16) float y1[128];
  __shared__ __align__(16) float hbuf[256];
  __shared__ __align__(16) float h1[256];
  __shared__ float4 c4v[64], s4v[64];    // select tables: [idx] -> (cos/sin(ts[s][idx]/2)) for s=0..3
  __shared__ float4 q4v[32], sq4v[32];   // qff tables (uniform across s)
  __shared__ float cprA[8], sprA[8];     // prep half-angle trig
  __shared__ float csg[4], ssg[4];       // signal angles
  __shared__ float hd[NOBS][4], hx[NOBS][6], hy[NOBS][6];
  __shared__ __align__(16) float sre[1024];
  __shared__ __align__(16) float smm[1024];

  const int lane = threadIdx.x;
  const int b = blockIdx.x;

  // ===== Phase A: MLP (per-wave) =====
  {
    float tb = t[b];
    float fr = expf(-logf(10000.f) * (float)lane / 64.f);
    float arg = tb * fr;
    emb[lane]      = cosf(arg);
    emb[64 + lane] = sinf(arg);
  }
  __syncthreads();
#pragma unroll
  for (int hh = 0; hh < 2; ++hh) {
    int o = lane + hh * 64;
    const float4* w4 = (const float4*)(te_w1 + o * 128);
    const float4* e4 = (const float4*)emb;
    float acc = te_b1[o];
#pragma unroll 8
    for (int j = 0; j < 32; ++j) {
      float4 w = w4[j], e = e4[j];
      acc += w.x*e.x + w.y*e.y + w.z*e.z + w.w*e.w;
    }
    y1[o] = acc / (1.f + expf(-acc));
  }
  __syncthreads();
#pragma unroll
  for (int hh = 0; hh < 2; ++hh) {
    int o = lane + hh * 64;
    const float4* w4 = (const float4*)(te_w2 + o * 128);
    const float4* e4 = (const float4*)y1;
    float acc = te_b2[o];
#pragma unroll 8
    for (int j = 0; j < 32; ++j) {
      float4 w = w4[j], e = e4[j];
      acc += w.x*e.x + w.y*e.y + w.z*e.z + w.w*e.w;
    }
    hbuf[128 + o] = acc;
    hbuf[o] = z_t[b * 128 + o];
  }
  __syncthreads();
#pragma unroll
  for (int q = 0; q < 4; ++q) {
    int o = lane + q * 64;
    const float4* w4 = (const float4*)(ip_w1 + o * 256);
    const float4* e4 = (const float4*)hbuf;
    float acc = ip_b1[o];
#pragma unroll 8
    for (int j = 0; j < 64; ++j) {
      float4 w = w4[j], e = e4[j];
      acc += w.x*e.x + w.y*e.y + w.z*e.z + w.w*e.w;
    }
    h1[o] = acc / (1.f + expf(-acc));
  }
  __syncthreads();
  {
    float cs[4], ss[4];
#pragma unroll
    for (int s = 0; s < 4; ++s) {
      int row = s * 64 + lane;
      const float4* w4 = (const float4*)(ip_w2 + row * 256);
      const float4* e4 = (const float4*)h1;
      float acc = ip_b2[row];
#pragma unroll 8
      for (int j = 0; j < 64; ++j) {
        float4 w = w4[j], e = e4[j];
        acc += w.x*e.x + w.y*e.y + w.z*e.z + w.w*e.w;
      }
      float theta = (1.f / (1.f + expf(-acc))) * TWO_PI_F;
      cs[s] = cosf(0.5f * theta);
      ss[s] = sinf(0.5f * theta);
    }
    c4v[lane] = make_float4(cs[0], cs[1], cs[2], cs[3]);
    s4v[lane] = make_float4(ss[0], ss[1], ss[2], ss[3]);
  }

  // ===== Phase B: small tables =====
  if (lane < 8)  { float a = prep_p[lane]; cprA[lane] = cosf(0.5f*a); sprA[lane] = sinf(0.5f*a); }
  if (lane < 4)  { float a = sig[lane]; csg[lane] = cosf(a); ssg[lane] = sinf(a); }
  if (lane < 32) { float a = qff[lane]; float c = cosf(0.5f*a), s = sinf(0.5f*a);
                   q4v[lane] = make_float4(c,c,c,c); sq4v[lane] = make_float4(s,s,s,s); }
  if (lane < NOBS) {
    int w = lane;
    hd[w][0] = 2.f * D_obs[w*4 + 1];
    hd[w][1] = 2.f * D_obs[w*4 + 2];
    hd[w][2] = 2.f * D_obs[w*4 + 3];
    hd[w][3] = 0.f;
#pragma unroll
    for (int k = 0; k < 6; ++k) { hx[w][k] = A_obs[w*6 + k]; hy[w][k] = B_obs[w*6 + k]; }
  }
  __syncthreads();

  // ===== Phase C: circuit, state fully in registers =====
  float vr[16], vi[16];
#pragma unroll
  for (int r = 0; r < 16; ++r) { vr[r] = 0.f; vi[r] = 0.f; }
  if (lane == 0) vr[0] = 1.f;

  pcphase(vr, vi, csg[0], ssg[0]);

  for (int k = 0; k < 3; ++k) {
    // prepare (forward)
    for (int ly = 0; ly < 2; ++ly) {
      {
        float cy = cprA[ly*4+0], sy = sprA[ly*4+0], cz = cprA[ly*4+1], sz = sprA[ly*4+1];
        g1q<2>(vr, vi,  cy*cz, -cy*sz,  -sy*cz,  sy*sz,   sy*cz,  sy*sz,  cy*cz,  cy*sz);
      }
      {
        float cy = cprA[ly*4+2], sy = sprA[ly*4+2], cz = cprA[ly*4+3], sz = sprA[ly*4+3];
        g1q<1>(vr, vi,  cy*cz, -cy*sz,  -sy*cz,  sy*sz,   sy*cz,  sy*sz,  cy*cz,  cy*sz);
      }
      cnot_anc(vr, vi);
    }
    // select (fwd for even k, adjoint for odd k)
    if (k & 1) {
      for (int l = 1; l >= 0; --l) sim14_adj(vr, vi, lane, c4v, s4v, l*32);
    } else {
      for (int l = 0; l < 2; ++l)  sim14_fwd(vr, vi, lane, c4v, s4v, l*32, 1.f);
    }
    // prepare (adjoint)
    for (int ly = 1; ly >= 0; --ly) {
      cnot_anc(vr, vi);
      {
        float cy = cprA[ly*4+2], sy = sprA[ly*4+2], cz = cprA[ly*4+3], sz = sprA[ly*4+3];
        g1q<1>(vr, vi,  cy*cz,  cy*sz,   sy*cz, -sy*sz,  -sy*cz, -sy*sz,  cy*cz, -cy*sz);
      }
      {
        float cy = cprA[ly*4+0], sy = sprA[ly*4+0], cz = cprA[ly*4+1], sz = sprA[ly*4+1];
        g1q<2>(vr, vi,  cy*cz,  cy*sz,   sy*cz, -sy*sz,  -sy*cz, -sy*sz,  cy*cz, -cy*sz);
      }
    }
    pcphase(vr, vi, csg[k+1], ssg[k+1]);
  }

  // final sim14, 1 layer, uniform qff angles
  sim14_fwd(vr, vi, lane, q4v, sq4v, 0, 1.f);

  // ===== Phase D: dump state, observables =====
  {
    float4* r4 = (float4*)sre;
    float4* i4 = (float4*)smm;
    r4[lane*4+0] = make_float4(vr[0],  vr[1],  vr[2],  vr[3]);
    r4[lane*4+1] = make_float4(vr[4],  vr[5],  vr[6],  vr[7]);
    r4[lane*4+2] = make_float4(vr[8],  vr[9],  vr[10], vr[11]);
    r4[lane*4+3] = make_float4(vr[12], vr[13], vr[14], vr[15]);
    i4[lane*4+0] = make_float4(vi[0],  vi[1],  vi[2],  vi[3]);
    i4[lane*4+1] = make_float4(vi[4],  vi[5],  vi[6],  vi[7]);
    i4[lane*4+2] = make_float4(vi[8],  vi[9],  vi[10], vi[11]);
    i4[lane*4+3] = make_float4(vi[12], vi[13], vi[14], vi[15]);
  }
  __syncthreads();

  float evv[NOBS];
#pragma unroll
  for (int w = 0; w < NOBS; ++w) {
    const int pb = 8 - w;  // wires (w,w+1) -> bits (9-w, 8-w)
    float a = 0.f;
#pragma unroll
    for (int q = 0; q < 4; ++q) {
      int tid_old = lane + q * 64;
      int ib = ((tid_old >> pb) << (pb + 2)) | (tid_old & ((1 << pb) - 1));
      float xr[4], xi[4];
#pragma unroll
      for (int i = 0; i < 4; ++i) { xr[i] = sre[ib + (i << pb)]; xi[i] = smm[ib + (i << pb)]; }
      a += hd[w][0] * (xr[0]*xr[0] + xi[0]*xi[0])
         + hd[w][1] * (xr[1]*xr[1] + xi[1]*xi[1])
         + hd[w][2] * (xr[2]*xr[2] + xi[2]*xi[2]);
      const int oi[6] = {1, 2, 2, 3, 3, 3};
      const int oj[6] = {0, 0, 1, 0, 1, 2};
#pragma unroll
      for (int k2 = 0; k2 < 6; ++k2) {
        int i = oi[k2], j = oj[k2];
        float rr = xr[i]*xr[j] + xi[i]*xi[j];
        float ii = xr[i]*xi[j] - xi[i]*xr[j];
        a += 2.f * (hx[w][k2]*rr - hy[w][k2]*ii);
      }
    }
    // butterfly reduce over 64 lanes (all lanes get the total)
#pragma unroll
    for (int o = 32; o > 0; o >>= 1) a += __shfl_xor(a, o, 64);
    evv[w] = a;
  }

  // ===== Phase E: head =====
#pragma unroll
  for (int hh = 0; hh < 2; ++hh) {
    int o = lane + hh * 64;
    float acc = head_b[o];
#pragma unroll
    for (int w = 0; w < NOBS; ++w) acc += evv[w] * head_w[o*NOBS + w];
    out[b * 128 + o] = acc;
  }
}

extern "C" void kernel_launch(void* const* d_in, const int* in_sizes, int n_in,
                              void* d_out, int out_size, void* d_ws, size_t ws_size,
                              hipStream_t stream) {
  (void)n_in; (void)out_size; (void)d_ws; (void)ws_size;
  const float* z_t    = (const float*)d_in[0];
  const float* t      = (const float*)d_in[1];
  const float* te_w1  = (const float*)d_in[2];
  const float* te_b1  = (const float*)d_in[3];
  const float* te_w2  = (const float*)d_in[4];
  const float* te_b2  = (const float*)d_in[5];
  const float* ip_w1  = (const float*)d_in[6];
  const float* ip_b1  = (const float*)d_in[7];
  const float* ip_w2  = (const float*)d_in[8];
  const float* ip_b2  = (const float*)d_in[9];
  const float* prep_p = (const float*)d_in[10];
  const float* sig    = (const float*)d_in[11];
  const float* qff    = (const float*)d_in[12];
  const float* A_obs  = (const float*)d_in[13];
  const float* B_obs  = (const float*)d_in[14];
  const float* D_obs  = (const float*)d_in[15];
  const float* head_w = (const float*)d_in[16];
  const float* head_b = (const float*)d_in[17];
  float* out = (float*)d_out;

  int B = in_sizes[1];  // t is (B,)
  qsvt_kernel<<<B, 64, 0, stream>>>(
      z_t, t, te_w1, te_b1, te_w2, te_b2, ip_w1, ip_b1, ip_w2, ip_b2,
      prep_p, sig, qff, A_obs, B_obs, D_obs, head_w, head_b, out);
}

// Round 3
// 144.347 us; speedup vs baseline: 1.4756x; 1.4756x over previous
//
#include <hip/hip_runtime.h>
#include <math.h>

#define NOBS 7
#define TWO_PI_F 6.283185307179586f

// Per-wave state layout: wave s (of 4) holds the 256 main-register amplitudes
// for ancilla value s. Within the wave: main index m (8 bits, wire w -> bit 7-w),
// m = lane*4 + r : lane bits = wires 0..5 (lane bit 5-w), reg bits r[1]=wire6, r[0]=wire7.

constexpr int REG_MASK(int w)  { return w==6 ? 2 : w==7 ? 1 : 0; }
constexpr int LANE_MASK(int w) { return w<=5 ? (1 << (5-w)) : 0; }

__device__ __forceinline__ float2 cmul(float2 a, float2 b) {
  return make_float2(a.x*b.x - a.y*b.y, a.x*b.y + a.y*b.x);
}
__device__ __forceinline__ float2 cmulc(float2 a, float2 b) {  // a * conj(b)
  return make_float2(a.x*b.x + a.y*b.y, a.y*b.x - a.x*b.y);
}
__device__ __forceinline__ float2 cadd(float2 a, float2 b) {
  return make_float2(a.x + b.x, a.y + b.y);
}

// ---------------- in-register gate helpers (4 amps/lane) ----------------

template<int W>
__device__ __forceinline__ void ry_gate(float* vr, float* vi, int lane,
                                        const float2* tab, int idx, float sg)
{
  float2 cs = tab[idx];
  float c = cs.x, s = sg * cs.y;
  if constexpr (REG_MASK(W) != 0) {
    constexpr int m = REG_MASK(W);
#pragma unroll
    for (int r = 0; r < 4; ++r) {
      if (r & m) continue;
      const int r1 = r | m;
      float a0 = vr[r], a1 = vr[r1];
      vr[r]  = c*a0 - s*a1;  vr[r1] = s*a0 + c*a1;
      float b0 = vi[r], b1 = vi[r1];
      vi[r]  = c*b0 - s*b1;  vi[r1] = s*b0 + c*b1;
    }
  } else {
    constexpr int LM = LANE_MASK(W);
    const float ls = (lane & LM) ? s : -s;
#pragma unroll
    for (int r = 0; r < 4; ++r) {
      float pr = __shfl_xor(vr[r], LM, 64);
      float pi = __shfl_xor(vi[r], LM, 64);
      vr[r] = c*vr[r] + ls*pr;
      vi[r] = c*vi[r] + ls*pi;
    }
  }
}

template<int WC, int WT>
__device__ __forceinline__ void crx_gate(float* vr, float* vi, int lane,
                                         const float2* tab, int idx, float sg)
{
  float2 cs = tab[idx];
  float c = cs.x, s = sg * cs.y;
  constexpr int MC = REG_MASK(WC), LC = LANE_MASK(WC);
  constexpr int MT = REG_MASK(WT), LT = LANE_MASK(WT);
  if constexpr (MC != 0 && MT != 0) {
#pragma unroll
    for (int r = 0; r < 4; ++r) {
      if (!(r & MC) || (r & MT)) continue;
      const int r1 = r | MT;
      float xr = vr[r], xi = vi[r], yr = vr[r1], yi = vi[r1];
      vr[r]  = c*xr + s*yi;  vi[r]  = c*xi - s*yr;
      vr[r1] = c*yr + s*xi;  vi[r1] = c*yi - s*xr;
    }
  } else if constexpr (MC != 0) {  // control reg-local, target lane bit
#pragma unroll
    for (int r = 0; r < 4; ++r) {
      if (!(r & MC)) continue;
      float pr = __shfl_xor(vr[r], LT, 64);
      float pi = __shfl_xor(vi[r], LT, 64);
      vr[r] = c*vr[r] + s*pi;
      vi[r] = c*vi[r] - s*pr;
    }
  } else if constexpr (MT != 0) {  // control lane bit, target reg-local
    const bool act = (lane & LC) != 0;
#pragma unroll
    for (int r = 0; r < 4; ++r) {
      if (r & MT) continue;
      const int r1 = r | MT;
      float xr = vr[r], xi = vi[r], yr = vr[r1], yi = vi[r1];
      float nxr = c*xr + s*yi, nxi = c*xi - s*yr;
      float nyr = c*yr + s*xi, nyi = c*yi - s*xr;
      vr[r]  = act ? nxr : xr;  vi[r]  = act ? nxi : xi;
      vr[r1] = act ? nyr : yr;  vi[r1] = act ? nyi : yi;
    }
  } else {  // both lane bits
    const bool act = (lane & LC) != 0;
#pragma unroll
    for (int r = 0; r < 4; ++r) {
      float pr = __shfl_xor(vr[r], LT, 64);
      float pi = __shfl_xor(vi[r], LT, 64);
      float nr = c*vr[r] + s*pi;
      float ni = c*vi[r] - s*pr;
      vr[r] = act ? nr : vr[r];
      vi[r] = act ? ni : vi[r];
    }
  }
}

// ---------------- sim14 layers (32 gates each) ----------------

__device__ __forceinline__ void sim14_fwd(float* vr, float* vi, int lane,
                                          const float2* tab, int off, float sg)
{
  ry_gate<0>(vr,vi,lane,tab,off+0,sg);  ry_gate<1>(vr,vi,lane,tab,off+1,sg);
  ry_gate<2>(vr,vi,lane,tab,off+2,sg);  ry_gate<3>(vr,vi,lane,tab,off+3,sg);
  ry_gate<4>(vr,vi,lane,tab,off+4,sg);  ry_gate<5>(vr,vi,lane,tab,off+5,sg);
  ry_gate<6>(vr,vi,lane,tab,off+6,sg);  ry_gate<7>(vr,vi,lane,tab,off+7,sg);
  crx_gate<7,0>(vr,vi,lane,tab,off+8,sg);  crx_gate<6,7>(vr,vi,lane,tab,off+9,sg);
  crx_gate<5,6>(vr,vi,lane,tab,off+10,sg); crx_gate<4,5>(vr,vi,lane,tab,off+11,sg);
  crx_gate<3,4>(vr,vi,lane,tab,off+12,sg); crx_gate<2,3>(vr,vi,lane,tab,off+13,sg);
  crx_gate<1,2>(vr,vi,lane,tab,off+14,sg); crx_gate<0,1>(vr,vi,lane,tab,off+15,sg);
  ry_gate<0>(vr,vi,lane,tab,off+16,sg); ry_gate<1>(vr,vi,lane,tab,off+17,sg);
  ry_gate<2>(vr,vi,lane,tab,off+18,sg); ry_gate<3>(vr,vi,lane,tab,off+19,sg);
  ry_gate<4>(vr,vi,lane,tab,off+20,sg); ry_gate<5>(vr,vi,lane,tab,off+21,sg);
  ry_gate<6>(vr,vi,lane,tab,off+22,sg); ry_gate<7>(vr,vi,lane,tab,off+23,sg);
  crx_gate<7,6>(vr,vi,lane,tab,off+24,sg); crx_gate<0,7>(vr,vi,lane,tab,off+25,sg);
  crx_gate<1,0>(vr,vi,lane,tab,off+26,sg); crx_gate<2,1>(vr,vi,lane,tab,off+27,sg);
  crx_gate<3,2>(vr,vi,lane,tab,off+28,sg); crx_gate<4,3>(vr,vi,lane,tab,off+29,sg);
  crx_gate<5,4>(vr,vi,lane,tab,off+30,sg); crx_gate<6,5>(vr,vi,lane,tab,off+31,sg);
}

__device__ __forceinline__ void sim14_adj(float* vr, float* vi, int lane,
                                          const float2* tab, int off)
{
  const float sg = -1.f;
  crx_gate<6,5>(vr,vi,lane,tab,off+31,sg); crx_gate<5,4>(vr,vi,lane,tab,off+30,sg);
  crx_gate<4,3>(vr,vi,lane,tab,off+29,sg); crx_gate<3,2>(vr,vi,lane,tab,off+28,sg);
  crx_gate<2,1>(vr,vi,lane,tab,off+27,sg); crx_gate<1,0>(vr,vi,lane,tab,off+26,sg);
  crx_gate<0,7>(vr,vi,lane,tab,off+25,sg); crx_gate<7,6>(vr,vi,lane,tab,off+24,sg);
  ry_gate<7>(vr,vi,lane,tab,off+23,sg); ry_gate<6>(vr,vi,lane,tab,off+22,sg);
  ry_gate<5>(vr,vi,lane,tab,off+21,sg); ry_gate<4>(vr,vi,lane,tab,off+20,sg);
  ry_gate<3>(vr,vi,lane,tab,off+19,sg); ry_gate<2>(vr,vi,lane,tab,off+18,sg);
  ry_gate<1>(vr,vi,lane,tab,off+17,sg); ry_gate<0>(vr,vi,lane,tab,off+16,sg);
  crx_gate<0,1>(vr,vi,lane,tab,off+15,sg); crx_gate<1,2>(vr,vi,lane,tab,off+14,sg);
  crx_gate<2,3>(vr,vi,lane,tab,off+13,sg); crx_gate<3,4>(vr,vi,lane,tab,off+12,sg);
  crx_gate<4,5>(vr,vi,lane,tab,off+11,sg); crx_gate<5,6>(vr,vi,lane,tab,off+10,sg);
  crx_gate<6,7>(vr,vi,lane,tab,off+9,sg);  crx_gate<7,0>(vr,vi,lane,tab,off+8,sg);
  ry_gate<7>(vr,vi,lane,tab,off+7,sg); ry_gate<6>(vr,vi,lane,tab,off+6,sg);
  ry_gate<5>(vr,vi,lane,tab,off+5,sg); ry_gate<4>(vr,vi,lane,tab,off+4,sg);
  ry_gate<3>(vr,vi,lane,tab,off+3,sg); ry_gate<2>(vr,vi,lane,tab,off+2,sg);
  ry_gate<1>(vr,vi,lane,tab,off+1,sg); ry_gate<0>(vr,vi,lane,tab,off+0,sg);
}

// ---------------- main kernel: 256 threads = 4 waves, one batch elem/block ----------------

__global__ __launch_bounds__(256) void qsvt_kernel(
    const float* __restrict__ z_t, const float* __restrict__ t,
    const float* __restrict__ te_w1, const float* __restrict__ te_b1,
    const float* __restrict__ te_w2, const float* __restrict__ te_b2,
    const float* __restrict__ ip_w1, const float* __restrict__ ip_b1,
    const float* __restrict__ ip_w2, const float* __restrict__ ip_b2,
    const float* __restrict__ prep_p, const float* __restrict__ sig,
    const float* __restrict__ qff, const float* __restrict__ A_obs,
    const float* __restrict__ B_obs, const float* __restrict__ D_obs,
    const float* __restrict__ head_w, const float* __restrict__ head_b,
    float* __restrict__ out)
{
  __shared__ __align__(16) float emb[128];
  __shared__ __align__(16) float y1[128];
  __shared__ __align__(16) float hbuf[256];
  __shared__ __align__(16) float h1[256];
  __shared__ __align__(16) float2 seltab[256];  // [s*64+g] -> (cos(th/2), sin(th/2))
  __shared__ __align__(16) float2 qtab[32];
  __shared__ __align__(16) float2 xbuf[64*17];  // exchange: lane region stride 17 float2
  __shared__ __align__(16) float dumpR[4][256];
  __shared__ __align__(16) float dumpI[4][256];
  __shared__ float redbuf[NOBS][4];

  const int tid  = threadIdx.x;
  const int lane = tid & 63;
  const int s    = tid >> 6;   // wave id == ancilla value
  const int b    = blockIdx.x;

  // ===== Phase A: MLP (all 256 threads) =====
  if (tid < 64) {
    float tb = t[b];
    float fr = expf(-logf(10000.f) * (float)tid / 64.f);
    float arg = tb * fr;
    emb[tid]      = cosf(arg);
    emb[64 + tid] = sinf(arg);
  }
  __syncthreads();
  if (tid < 128) {
    const float4* w4 = (const float4*)(te_w1 + tid * 128);
    const float4* e4 = (const float4*)emb;
    float acc = te_b1[tid];
#pragma unroll 8
    for (int j = 0; j < 32; ++j) {
      float4 w = w4[j], e = e4[j];
      acc += w.x*e.x + w.y*e.y + w.z*e.z + w.w*e.w;
    }
    y1[tid] = acc / (1.f + expf(-acc));
  }
  __syncthreads();
  if (tid < 128) {
    const float4* w4 = (const float4*)(te_w2 + tid * 128);
    const float4* e4 = (const float4*)y1;
    float acc = te_b2[tid];
#pragma unroll 8
    for (int j = 0; j < 32; ++j) {
      float4 w = w4[j], e = e4[j];
      acc += w.x*e.x + w.y*e.y + w.z*e.z + w.w*e.w;
    }
    hbuf[128 + tid] = acc;
  } else {
    hbuf[tid - 128] = z_t[b * 128 + (tid - 128)];
  }
  __syncthreads();
  {
    const float4* w4 = (const float4*)(ip_w1 + tid * 256);
    const float4* e4 = (const float4*)hbuf;
    float acc = ip_b1[tid];
#pragma unroll 8
    for (int j = 0; j < 64; ++j) {
      float4 w = w4[j], e = e4[j];
      acc += w.x*e.x + w.y*e.y + w.z*e.z + w.w*e.w;
    }
    h1[tid] = acc / (1.f + expf(-acc));
  }
  __syncthreads();
  {
    const float4* w4 = (const float4*)(ip_w2 + tid * 256);
    const float4* e4 = (const float4*)h1;
    float acc = ip_b2[tid];
#pragma unroll 8
    for (int j = 0; j < 64; ++j) {
      float4 w = w4[j], e = e4[j];
      acc += w.x*e.x + w.y*e.y + w.z*e.z + w.w*e.w;
    }
    float theta = (1.f / (1.f + expf(-acc))) * TWO_PI_F;
    seltab[tid] = make_float2(cosf(0.5f * theta), sinf(0.5f * theta));
  }
  if (tid < 32) {
    float a = qff[tid];
    qtab[tid] = make_float2(cosf(0.5f * a), sinf(0.5f * a));
  }

  // ===== Phase B: per-thread 4x4 ancilla matrices (registers) =====
  // G(y,z) = Rz(z)Ry(y): rows (cy e^{-iz/2}, -sy e^{-iz/2} ; sy e^{+iz/2}, cy e^{+iz/2})
  float2 Ga[2][2][2], Gb[2][2][2];
#pragma unroll
  for (int ly = 0; ly < 2; ++ly) {
#pragma unroll
    for (int qi = 0; qi < 2; ++qi) {
      float y = prep_p[ly*4 + qi*2 + 0], z = prep_p[ly*4 + qi*2 + 1];
      float cy = cosf(0.5f*y), sy = sinf(0.5f*y), cz = cosf(0.5f*z), sz = sinf(0.5f*z);
      float2 g00 = make_float2( cy*cz, -cy*sz);
      float2 g01 = make_float2(-sy*cz,  sy*sz);
      float2 g10 = make_float2( sy*cz,  sy*sz);
      float2 g11 = make_float2( cy*cz,  cy*sz);
      if (qi == 0) { Ga[ly][0][0]=g00; Ga[ly][0][1]=g01; Ga[ly][1][0]=g10; Ga[ly][1][1]=g11; }
      else         { Gb[ly][0][0]=g00; Gb[ly][0][1]=g01; Gb[ly][1][0]=g10; Gb[ly][1][1]=g11; }
    }
  }
  // M_ly = CNOT(ctrl bit1, tgt bit0) * (Ga_ly (x) Gb_ly)  -> rows 2,3 swapped
  float2 M[2][4][4];
#pragma unroll
  for (int ly = 0; ly < 2; ++ly) {
    float2 T[4][4];
#pragma unroll
    for (int i = 0; i < 4; ++i)
#pragma unroll
      for (int j = 0; j < 4; ++j)
        T[i][j] = cmul(Ga[ly][i>>1][j>>1], Gb[ly][i&1][j&1]);
#pragma unroll
    for (int j = 0; j < 4; ++j) {
      M[ly][0][j] = T[0][j]; M[ly][1][j] = T[1][j];
      M[ly][2][j] = T[3][j]; M[ly][3][j] = T[2][j];
    }
  }
  float2 U[4][4];
#pragma unroll
  for (int i = 0; i < 4; ++i)
#pragma unroll
    for (int j = 0; j < 4; ++j) {
      float2 acc = make_float2(0.f, 0.f);
#pragma unroll
      for (int kk = 0; kk < 4; ++kk) acc = cadd(acc, cmul(M[1][i][kk], M[0][kk][j]));
      U[i][j] = acc;
    }
  // wave-specific row/col of U (select by s, keep in registers)
  float2 Urow[4], Ucol[4];
#pragma unroll
  for (int j = 0; j < 4; ++j) {
    Urow[j] = s==0 ? U[0][j] : s==1 ? U[1][j] : s==2 ? U[2][j] : U[3][j];
    Ucol[j] = s==0 ? U[j][0] : s==1 ? U[j][1] : s==2 ? U[j][2] : U[j][3];
  }
  float sg0 = sig[0], sg1 = sig[1], sg2 = sig[2], sg3 = sig[3];
  float c1 = cosf(sg1), s1v = sinf(sg1);
  float c2 = cosf(sg2), s2v = sinf(sg2);
  float c3 = cosf(sg3), s3v = sinf(sg3);
  // rows of X1 = U D1 U^, X2 = U D2 U^, F = D3 U^   (D_k = diag(e^{+i sg}, e^{-i sg} x3))
  float2 R1[4], R2[4], RF[4];
  {
    float s3s = (s == 0) ? s3v : -s3v;
    float2 d3 = make_float2(c3, s3s);
#pragma unroll
    for (int sp = 0; sp < 4; ++sp) {
      float2 a1 = make_float2(0.f, 0.f), a2 = make_float2(0.f, 0.f);
#pragma unroll
      for (int j = 0; j < 4; ++j) {
        float2 uspj = sp==0 ? U[0][j] : sp==1 ? U[1][j] : sp==2 ? U[2][j] : U[3][j];
        float2 tt = cmulc(Urow[j], uspj);            // U[s][j] * conj(U[sp][j])
        float sj = (j == 0) ? 1.f : -1.f;
        a1 = cadd(a1, cmul(tt, make_float2(c1, sj*s1v)));
        a2 = cadd(a2, cmul(tt, make_float2(c2, sj*s2v)));
      }
      R1[sp] = a1; R2[sp] = a2;
      RF[sp] = cmul(d3, make_float2(Ucol[sp].x, -Ucol[sp].y));  // D3[s]*conj(U[sp][s])
    }
  }
  __syncthreads();  // seltab/qtab visible to all waves

  // ===== Phase C: circuit. init = U * D0 * |0..0> : only m=0 nonzero =====
  float vr[4], vi[4];
  {
    float2 a0 = cmul(Urow[0], make_float2(cosf(sg0), sinf(sg0)));
#pragma unroll
    for (int r = 0; r < 4; ++r) { vr[r] = 0.f; vi[r] = 0.f; }
    if (lane == 0) { vr[0] = a0.x; vi[0] = a0.y; }
  }
  const float2* stab = &seltab[s * 64];

  // select_0 (fwd)
  sim14_fwd(vr, vi, lane, stab, 0, 1.f);
  sim14_fwd(vr, vi, lane, stab, 32, 1.f);
  // exchange X1
  {
#pragma unroll
    for (int r = 0; r < 4; ++r) xbuf[lane*17 + r*4 + s] = make_float2(vr[r], vi[r]);
    __syncthreads();
#pragma unroll
    for (int r = 0; r < 4; ++r) {
      const float2* p = &xbuf[lane*17 + r*4];
      float2 o = cmul(R1[0], p[0]);
      o = cadd(o, cmul(R1[1], p[1]));
      o = cadd(o, cmul(R1[2], p[2]));
      o = cadd(o, cmul(R1[3], p[3]));
      vr[r] = o.x; vi[r] = o.y;
    }
    __syncthreads();
  }
  // select_1 (adjoint)
  sim14_adj(vr, vi, lane, stab, 32);
  sim14_adj(vr, vi, lane, stab, 0);
  // exchange X2
  {
#pragma unroll
    for (int r = 0; r < 4; ++r) xbuf[lane*17 + r*4 + s] = make_float2(vr[r], vi[r]);
    __syncthreads();
#pragma unroll
    for (int r = 0; r < 4; ++r) {
      const float2* p = &xbuf[lane*17 + r*4];
      float2 o = cmul(R2[0], p[0]);
      o = cadd(o, cmul(R2[1], p[1]));
      o = cadd(o, cmul(R2[2], p[2]));
      o = cadd(o, cmul(R2[3], p[3]));
      vr[r] = o.x; vi[r] = o.y;
    }
    __syncthreads();
  }
  // select_2 (fwd)
  sim14_fwd(vr, vi, lane, stab, 0, 1.f);
  sim14_fwd(vr, vi, lane, stab, 32, 1.f);
  // exchange F = D3 U^
  {
#pragma unroll
    for (int r = 0; r < 4; ++r) xbuf[lane*17 + r*4 + s] = make_float2(vr[r], vi[r]);
    __syncthreads();
#pragma unroll
    for (int r = 0; r < 4; ++r) {
      const float2* p = &xbuf[lane*17 + r*4];
      float2 o = cmul(RF[0], p[0]);
      o = cadd(o, cmul(RF[1], p[1]));
      o = cadd(o, cmul(RF[2], p[2]));
      o = cadd(o, cmul(RF[3], p[3]));
      vr[r] = o.x; vi[r] = o.y;
    }
    __syncthreads();
  }
  // final sim14 layer with qff angles (uniform across s)
  sim14_fwd(vr, vi, lane, qtab, 0, 1.f);

  // ===== Phase D: dump (wave-local), observables =====
  *(float4*)&dumpR[s][lane*4] = make_float4(vr[0], vr[1], vr[2], vr[3]);
  *(float4*)&dumpI[s][lane*4] = make_float4(vi[0], vi[1], vi[2], vi[3]);
  // same-wave LDS RAW: ordered by lgkmcnt, no barrier needed

#pragma unroll
  for (int w = 0; w < NOBS; ++w) {
    const int pb = 6 - w;  // wires (w, w+1) -> bits (7-w, 6-w) of m
    int g = lane;
    int ib = ((g >> pb) << (pb + 2)) | (g & ((1 << pb) - 1));
    float xr[4], xi[4];
#pragma unroll
    for (int i = 0; i < 4; ++i) { xr[i] = dumpR[s][ib + (i << pb)]; xi[i] = dumpI[s][ib + (i << pb)]; }
    float hd0 = 2.f * D_obs[w*4 + 1];
    float hd1 = 2.f * D_obs[w*4 + 2];
    float hd2 = 2.f * D_obs[w*4 + 3];
    float a = hd0 * (xr[0]*xr[0] + xi[0]*xi[0])
            + hd1 * (xr[1]*xr[1] + xi[1]*xi[1])
            + hd2 * (xr[2]*xr[2] + xi[2]*xi[2]);
    const int oi[6] = {1, 2, 2, 3, 3, 3};
    const int oj[6] = {0, 0, 1, 0, 1, 2};
#pragma unroll
    for (int k2 = 0; k2 < 6; ++k2) {
      int i = oi[k2], j = oj[k2];
      float rr = xr[i]*xr[j] + xi[i]*xi[j];   // Re(conj(v_i) v_j)
      float ii = xr[i]*xi[j] - xi[i]*xr[j];   // Im(conj(v_i) v_j)
      a += 2.f * (A_obs[w*6 + k2]*rr - B_obs[w*6 + k2]*ii);
    }
#pragma unroll
    for (int o = 32; o > 0; o >>= 1) a += __shfl_xor(a, o, 64);
    if (lane == 0) redbuf[w][s] = a;
  }
  __syncthreads();

  // ===== Phase E: head =====
  if (tid < 128) {
    float acc = head_b[tid];
#pragma unroll
    for (int w = 0; w < NOBS; ++w) {
      float ev = redbuf[w][0] + redbuf[w][1] + redbuf[w][2] + redbuf[w][3];
      acc += ev * head_w[tid*NOBS + w];
    }
    out[b * 128 + tid] = acc;
  }
}

extern "C" void kernel_launch(void* const* d_in, const int* in_sizes, int n_in,
                              void* d_out, int out_size, void* d_ws, size_t ws_size,
                              hipStream_t stream) {
  (void)n_in; (void)out_size; (void)d_ws; (void)ws_size;
  const float* z_t    = (const float*)d_in[0];
  const float* t      = (const float*)d_in[1];
  const float* te_w1  = (const float*)d_in[2];
  const float* te_b1  = (const float*)d_in[3];
  const float* te_w2  = (const float*)d_in[4];
  const float* te_b2  = (const float*)d_in[5];
  const float* ip_w1  = (const float*)d_in[6];
  const float* ip_b1  = (const float*)d_in[7];
  const float* ip_w2  = (const float*)d_in[8];
  const float* ip_b2  = (const float*)d_in[9];
  const float* prep_p = (const float*)d_in[10];
  const float* sig    = (const float*)d_in[11];
  const float* qff    = (const float*)d_in[12];
  const float* A_obs  = (const float*)d_in[13];
  const float* B_obs  = (const float*)d_in[14];
  const float* D_obs  = (const float*)d_in[15];
  const float* head_w = (const float*)d_in[16];
  const float* head_b = (const float*)d_in[17];
  float* out = (float*)d_out;

  int B = in_sizes[1];  // t is (B,)
  qsvt_kernel<<<B, 256, 0, stream>>>(
      z_t, t, te_w1, te_b1, te_w2, te_b2, ip_w1, ip_b1, ip_w2, ip_b2,
      prep_p, sig, qff, A_obs, B_obs, D_obs, head_w, head_b, out);
}

// Round 5
// 128.828 us; speedup vs baseline: 1.6534x; 1.1205x over previous
//
#include <hip/hip_runtime.h>
#include <math.h>

#define NOBS 7
#define TWO_PI_F 6.283185307179586f
#define PI_F 3.14159265358979f

// Per-wave state layout: wave s (of 4) holds the 256 main-register amplitudes
// for ancilla value s. Within the wave: main index m (8 bits, wire w -> bit 7-w),
// m = lane*4 + r : lane bits = wires 0..5 (lane bit 5-w), reg bits r[1]=wire6, r[0]=wire7.

constexpr int REG_MASK(int w)  { return w==6 ? 2 : w==7 ? 1 : 0; }
constexpr int LANE_MASK(int w) { return w<=5 ? (1 << (5-w)) : 0; }

// xor-lane exchange: DPP quad_perm for masks 1,2 (4-cycle VALU), LDS shfl otherwise
template<int LM>
__device__ __forceinline__ float lane_xor(float x) {
  if constexpr (LM == 1)
    return __int_as_float(__builtin_amdgcn_mov_dpp(__float_as_int(x), 0xB1, 0xF, 0xF, true));
  else if constexpr (LM == 2)
    return __int_as_float(__builtin_amdgcn_mov_dpp(__float_as_int(x), 0x4E, 0xF, 0xF, true));
  else
    return __shfl_xor(x, LM, 64);
}

__device__ __forceinline__ float2 cmul(float2 a, float2 b) {
  return make_float2(a.x*b.x - a.y*b.y, a.x*b.y + a.y*b.x);
}
__device__ __forceinline__ float2 cmulc(float2 a, float2 b) {  // a * conj(b)
  return make_float2(a.x*b.x + a.y*b.y, a.y*b.x - a.x*b.y);
}
__device__ __forceinline__ float2 cadd(float2 a, float2 b) {
  return make_float2(a.x + b.x, a.y + b.y);
}

// ---------------- in-register gate helpers (4 amps/lane) ----------------

template<int W>
__device__ __forceinline__ void ry_gate(float* vr, float* vi, int lane,
                                        const float2* tab, int idx, float sg)
{
  float2 cs = tab[idx];
  float c = cs.x, s = sg * cs.y;
  if constexpr (REG_MASK(W) != 0) {
    constexpr int m = REG_MASK(W);
#pragma unroll
    for (int r = 0; r < 4; ++r) {
      if (r & m) continue;
      const int r1 = r | m;
      float a0 = vr[r], a1 = vr[r1];
      vr[r]  = c*a0 - s*a1;  vr[r1] = s*a0 + c*a1;
      float b0 = vi[r], b1 = vi[r1];
      vi[r]  = c*b0 - s*b1;  vi[r1] = s*b0 + c*b1;
    }
  } else {
    constexpr int LM = LANE_MASK(W);
    const float ls = (lane & LM) ? s : -s;
#pragma unroll
    for (int r = 0; r < 4; ++r) {
      float pr = lane_xor<LM>(vr[r]);
      float pi = lane_xor<LM>(vi[r]);
      vr[r] = c*vr[r] + ls*pr;
      vi[r] = c*vi[r] + ls*pi;
    }
  }
}

template<int WC, int WT>
__device__ __forceinline__ void crx_gate(float* vr, float* vi, int lane,
                                         const float2* tab, int idx, float sg)
{
  float2 cs = tab[idx];
  float c = cs.x, s = sg * cs.y;
  constexpr int MC = REG_MASK(WC), LC = LANE_MASK(WC);
  constexpr int MT = REG_MASK(WT), LT = LANE_MASK(WT);
  if constexpr (MC != 0 && MT != 0) {
#pragma unroll
    for (int r = 0; r < 4; ++r) {
      if (!(r & MC) || (r & MT)) continue;
      const int r1 = r | MT;
      float xr = vr[r], xi = vi[r], yr = vr[r1], yi = vi[r1];
      vr[r]  = c*xr + s*yi;  vi[r]  = c*xi - s*yr;
      vr[r1] = c*yr + s*xi;  vi[r1] = c*yi - s*xr;
    }
  } else if constexpr (MC != 0) {  // control reg-local, target lane bit
#pragma unroll
    for (int r = 0; r < 4; ++r) {
      if (!(r & MC)) continue;
      float pr = lane_xor<LT>(vr[r]);
      float pi = lane_xor<LT>(vi[r]);
      vr[r] = c*vr[r] + s*pi;
      vi[r] = c*vi[r] - s*pr;
    }
  } else if constexpr (MT != 0) {  // control lane bit, target reg-local
    const bool act = (lane & LC) != 0;
#pragma unroll
    for (int r = 0; r < 4; ++r) {
      if (r & MT) continue;
      const int r1 = r | MT;
      float xr = vr[r], xi = vi[r], yr = vr[r1], yi = vi[r1];
      float nxr = c*xr + s*yi, nxi = c*xi - s*yr;
      float nyr = c*yr + s*xi, nyi = c*yi - s*xr;
      vr[r]  = act ? nxr : xr;  vi[r]  = act ? nxi : xi;
      vr[r1] = act ? nyr : yr;  vi[r1] = act ? nyi : yi;
    }
  } else {  // both lane bits
    const bool act = (lane & LC) != 0;
#pragma unroll
    for (int r = 0; r < 4; ++r) {
      float pr = lane_xor<LT>(vr[r]);
      float pi = lane_xor<LT>(vi[r]);
      float nr = c*vr[r] + s*pi;
      float ni = c*vi[r] - s*pr;
      vr[r] = act ? nr : vr[r];
      vi[r] = act ? ni : vi[r];
    }
  }
}

// ---------------- sim14 layers (32 gates each) ----------------

__device__ __forceinline__ void sim14_fwd(float* vr, float* vi, int lane,
                                          const float2* tab, int off, float sg)
{
  ry_gate<0>(vr,vi,lane,tab,off+0,sg);  ry_gate<1>(vr,vi,lane,tab,off+1,sg);
  ry_gate<2>(vr,vi,lane,tab,off+2,sg);  ry_gate<3>(vr,vi,lane,tab,off+3,sg);
  ry_gate<4>(vr,vi,lane,tab,off+4,sg);  ry_gate<5>(vr,vi,lane,tab,off+5,sg);
  ry_gate<6>(vr,vi,lane,tab,off+6,sg);  ry_gate<7>(vr,vi,lane,tab,off+7,sg);
  crx_gate<7,0>(vr,vi,lane,tab,off+8,sg);  crx_gate<6,7>(vr,vi,lane,tab,off+9,sg);
  crx_gate<5,6>(vr,vi,lane,tab,off+10,sg); crx_gate<4,5>(vr,vi,lane,tab,off+11,sg);
  crx_gate<3,4>(vr,vi,lane,tab,off+12,sg); crx_gate<2,3>(vr,vi,lane,tab,off+13,sg);
  crx_gate<1,2>(vr,vi,lane,tab,off+14,sg); crx_gate<0,1>(vr,vi,lane,tab,off+15,sg);
  ry_gate<0>(vr,vi,lane,tab,off+16,sg); ry_gate<1>(vr,vi,lane,tab,off+17,sg);
  ry_gate<2>(vr,vi,lane,tab,off+18,sg); ry_gate<3>(vr,vi,lane,tab,off+19,sg);
  ry_gate<4>(vr,vi,lane,tab,off+20,sg); ry_gate<5>(vr,vi,lane,tab,off+21,sg);
  ry_gate<6>(vr,vi,lane,tab,off+22,sg); ry_gate<7>(vr,vi,lane,tab,off+23,sg);
  crx_gate<7,6>(vr,vi,lane,tab,off+24,sg); crx_gate<0,7>(vr,vi,lane,tab,off+25,sg);
  crx_gate<1,0>(vr,vi,lane,tab,off+26,sg); crx_gate<2,1>(vr,vi,lane,tab,off+27,sg);
  crx_gate<3,2>(vr,vi,lane,tab,off+28,sg); crx_gate<4,3>(vr,vi,lane,tab,off+29,sg);
  crx_gate<5,4>(vr,vi,lane,tab,off+30,sg); crx_gate<6,5>(vr,vi,lane,tab,off+31,sg);
}

__device__ __forceinline__ void sim14_adj(float* vr, float* vi, int lane,
                                          const float2* tab, int off)
{
  const float sg = -1.f;
  crx_gate<6,5>(vr,vi,lane,tab,off+31,sg); crx_gate<5,4>(vr,vi,lane,tab,off+30,sg);
  crx_gate<4,3>(vr,vi,lane,tab,off+29,sg); crx_gate<3,2>(vr,vi,lane,tab,off+28,sg);
  crx_gate<2,1>(vr,vi,lane,tab,off+27,sg); crx_gate<1,0>(vr,vi,lane,tab,off+26,sg);
  crx_gate<0,7>(vr,vi,lane,tab,off+25,sg); crx_gate<7,6>(vr,vi,lane,tab,off+24,sg);
  ry_gate<7>(vr,vi,lane,tab,off+23,sg); ry_gate<6>(vr,vi,lane,tab,off+22,sg);
  ry_gate<5>(vr,vi,lane,tab,off+21,sg); ry_gate<4>(vr,vi,lane,tab,off+20,sg);
  ry_gate<3>(vr,vi,lane,tab,off+19,sg); ry_gate<2>(vr,vi,lane,tab,off+18,sg);
  ry_gate<1>(vr,vi,lane,tab,off+17,sg); ry_gate<0>(vr,vi,lane,tab,off+16,sg);
  crx_gate<0,1>(vr,vi,lane,tab,off+15,sg); crx_gate<1,2>(vr,vi,lane,tab,off+14,sg);
  crx_gate<2,3>(vr,vi,lane,tab,off+13,sg); crx_gate<3,4>(vr,vi,lane,tab,off+12,sg);
  crx_gate<4,5>(vr,vi,lane,tab,off+11,sg); crx_gate<5,6>(vr,vi,lane,tab,off+10,sg);
  crx_gate<6,7>(vr,vi,lane,tab,off+9,sg);  crx_gate<7,0>(vr,vi,lane,tab,off+8,sg);
  ry_gate<7>(vr,vi,lane,tab,off+7,sg); ry_gate<6>(vr,vi,lane,tab,off+6,sg);
  ry_gate<5>(vr,vi,lane,tab,off+5,sg); ry_gate<4>(vr,vi,lane,tab,off+4,sg);
  ry_gate<3>(vr,vi,lane,tab,off+3,sg); ry_gate<2>(vr,vi,lane,tab,off+2,sg);
  ry_gate<1>(vr,vi,lane,tab,off+1,sg); ry_gate<0>(vr,vi,lane,tab,off+0,sg);
}

// ---------------- cooperative-row MLP layer ----------------
// 8 lanes per output row (sub = lane&7 covers 32 consecutive cols per iter =>
// each wave-level load = 8 contiguous 128B segments). 8 rows/pass, NP passes.
// MODE: 0 = silu->yl, 1 = raw->yl, 2 = seltab ((float2*)yl)

template<int IN, int NP, int MODE>
__device__ __forceinline__ void mlp_layer(const float* __restrict__ W,
    const float* __restrict__ bias, const float* xl, float* yl,
    int rbase, int lane)
{
  const int sub = lane & 7;
  const int g   = lane >> 3;
#pragma unroll
  for (int p = 0; p < NP; ++p) {
    const int row = rbase + p * 8 + g;
    const float4* w4 = (const float4*)(W + row * IN) + sub;
    const float4* x4 = (const float4*)xl + sub;
    float acc = 0.f;
#pragma unroll
    for (int it = 0; it < IN / 32; ++it) {
      float4 w = w4[it * 8], e = x4[it * 8];
      acc += w.x*e.x + w.y*e.y + w.z*e.z + w.w*e.w;
    }
    acc += lane_xor<1>(acc);
    acc += lane_xor<2>(acc);
    acc += __shfl_xor(acc, 4, 64);
    if (sub == 0) {
      float a = acc + bias[row];
      if constexpr (MODE == 0) {
        yl[row] = a / (1.f + __expf(-a));
      } else if constexpr (MODE == 1) {
        yl[row] = a;
      } else {
        float th = PI_F / (1.f + __expf(-a));   // theta/2 = pi * sigmoid(a)
        float sn, cn;
        __sincosf(th, &sn, &cn);
        ((float2*)yl)[row] = make_float2(cn, sn);
      }
    }
  }
}

// ---------------- main kernel: 256 threads = 4 waves, one batch elem/block ----------------

__global__ __launch_bounds__(256) void qsvt_kernel(
    const float* __restrict__ z_t, const float* __restrict__ t,
    const float* __restrict__ te_w1, const float* __restrict__ te_b1,
    const float* __restrict__ te_w2, const float* __restrict__ te_b2,
    const float* __restrict__ ip_w1, const float* __restrict__ ip_b1,
    const float* __restrict__ ip_w2, const float* __restrict__ ip_b2,
    const float* __restrict__ prep_p, const float* __restrict__ sig,
    const float* __restrict__ qff, const float* __restrict__ A_obs,
    const float* __restrict__ B_obs, const float* __restrict__ D_obs,
    const float* __restrict__ head_w, const float* __restrict__ head_b,
    float* __restrict__ out)
{
  __shared__ __align__(16) float emb[128];
  __shared__ __align__(16) float y1[128];
  __shared__ __align__(16) float hbuf[256];
  __shared__ __align__(16) float h1[256];
  __shared__ __align__(16) float2 seltab[256];  // [s*64+g] -> (cos(th/2), sin(th/2))
  __shared__ __align__(16) float2 qtab[32];
  __shared__ __align__(16) float2 xbuf[64*17];  // exchange: lane region stride 17 float2
  __shared__ __align__(16) float dumpR[4][256];
  __shared__ __align__(16) float dumpI[4][256];
  __shared__ float redbuf[NOBS][4];
  __shared__ float hdc[NOBS][3], hxc[NOBS][6], hyc[NOBS][6];
  __shared__ __align__(16) float shw[128*NOBS];
  __shared__ __align__(16) float shb[128];

  const int tid  = threadIdx.x;
  const int lane = tid & 63;
  const int s    = tid >> 6;   // wave id == ancilla value
  const int b    = blockIdx.x;

  // ===== Phase A: MLP (cooperative rows) =====
  if (tid < 128) {
    int j = tid & 63;
    float fr = __expf(-9.210340371976184f * (float)j / 64.f);  // exp(-ln(1e4)*j/64)
    float arg = t[b] * fr;
    float sn, cn;
    __sincosf(arg, &sn, &cn);
    emb[tid] = (tid < 64) ? cn : sn;
  } else if (tid < 160) {
    int j = tid - 128;
    float sn, cn;
    __sincosf(0.5f * qff[j], &sn, &cn);
    qtab[j] = make_float2(cn, sn);
  }
  __syncthreads();

  mlp_layer<128, 4, 0>(te_w1, te_b1, emb, y1, s * 32, lane);
  if (tid < 128) hbuf[tid] = z_t[b * 128 + tid];
  __syncthreads();

  mlp_layer<128, 4, 1>(te_w2, te_b2, y1, hbuf + 128, s * 32, lane);
  __syncthreads();

  mlp_layer<256, 8, 0>(ip_w1, ip_b1, hbuf, h1, s * 64, lane);
  __syncthreads();

  mlp_layer<256, 8, 2>(ip_w2, ip_b2, h1, (float*)seltab, s * 64, lane);

  // prefetch observable + head coefficients into LDS (off the tail path)
  if (tid < NOBS * 6)      { hxc[tid/6][tid%6] = A_obs[tid]; hyc[tid/6][tid%6] = B_obs[tid]; }
  else if (tid >= 64 && tid < 64 + NOBS*3) { int q = tid - 64; hdc[q/3][q%3] = 2.f * D_obs[(q/3)*4 + (q%3) + 1]; }
#pragma unroll
  for (int i = tid; i < 128*NOBS; i += 256) shw[i] = head_w[i];
  if (tid < 128) shb[tid] = head_b[tid];

  // ===== Phase B: per-thread 4x4 ancilla matrices (registers) =====
  float2 Ga[2][2][2], Gb[2][2][2];
#pragma unroll
  for (int ly = 0; ly < 2; ++ly) {
#pragma unroll
    for (int qi = 0; qi < 2; ++qi) {
      float y = prep_p[ly*4 + qi*2 + 0], z = prep_p[ly*4 + qi*2 + 1];
      float cy, sy, cz, sz;
      __sincosf(0.5f*y, &sy, &cy);
      __sincosf(0.5f*z, &sz, &cz);
      float2 g00 = make_float2( cy*cz, -cy*sz);
      float2 g01 = make_float2(-sy*cz,  sy*sz);
      float2 g10 = make_float2( sy*cz,  sy*sz);
      float2 g11 = make_float2( cy*cz,  cy*sz);
      if (qi == 0) { Ga[ly][0][0]=g00; Ga[ly][0][1]=g01; Ga[ly][1][0]=g10; Ga[ly][1][1]=g11; }
      else         { Gb[ly][0][0]=g00; Gb[ly][0][1]=g01; Gb[ly][1][0]=g10; Gb[ly][1][1]=g11; }
    }
  }
  float2 M[2][4][4];
#pragma unroll
  for (int ly = 0; ly < 2; ++ly) {
    float2 T[4][4];
#pragma unroll
    for (int i = 0; i < 4; ++i)
#pragma unroll
      for (int j = 0; j < 4; ++j)
        T[i][j] = cmul(Ga[ly][i>>1][j>>1], Gb[ly][i&1][j&1]);
#pragma unroll
    for (int j = 0; j < 4; ++j) {
      M[ly][0][j] = T[0][j]; M[ly][1][j] = T[1][j];
      M[ly][2][j] = T[3][j]; M[ly][3][j] = T[2][j];
    }
  }
  float2 U[4][4];
#pragma unroll
  for (int i = 0; i < 4; ++i)
#pragma unroll
    for (int j = 0; j < 4; ++j) {
      float2 acc = make_float2(0.f, 0.f);
#pragma unroll
      for (int kk = 0; kk < 4; ++kk) acc = cadd(acc, cmul(M[1][i][kk], M[0][kk][j]));
      U[i][j] = acc;
    }
  float2 Urow[4], Ucol[4];
#pragma unroll
  for (int j = 0; j < 4; ++j) {
    Urow[j] = s==0 ? U[0][j] : s==1 ? U[1][j] : s==2 ? U[2][j] : U[3][j];
    Ucol[j] = s==0 ? U[j][0] : s==1 ? U[j][1] : s==2 ? U[j][2] : U[j][3];
  }
  float sg0 = sig[0], sg1 = sig[1], sg2 = sig[2], sg3 = sig[3];
  float c1, s1v, c2, s2v, c3, s3v;
  __sincosf(sg1, &s1v, &c1);
  __sincosf(sg2, &s2v, &c2);
  __sincosf(sg3, &s3v, &c3);
  float2 R1[4], R2[4], RF[4];
  {
    float s3s = (s == 0) ? s3v : -s3v;
    float2 d3 = make_float2(c3, s3s);
#pragma unroll
    for (int sp = 0; sp < 4; ++sp) {
      float2 a1 = make_float2(0.f, 0.f), a2 = make_float2(0.f, 0.f);
#pragma unroll
      for (int j = 0; j < 4; ++j) {
        float2 uspj = sp==0 ? U[0][j] : sp==1 ? U[1][j] : sp==2 ? U[2][j] : U[3][j];
        float2 tt = cmulc(Urow[j], uspj);            // U[s][j] * conj(U[sp][j])
        float sj = (j == 0) ? 1.f : -1.f;
        a1 = cadd(a1, cmul(tt, make_float2(c1, sj*s1v)));
        a2 = cadd(a2, cmul(tt, make_float2(c2, sj*s2v)));
      }
      R1[sp] = a1; R2[sp] = a2;
      RF[sp] = cmul(d3, make_float2(Ucol[sp].x, -Ucol[sp].y));  // D3[s]*conj(U[sp][s])
    }
  }
  __syncthreads();  // seltab/qtab/coefs visible to all waves

  // ===== Phase C: circuit. init = U * D0 * |0..0> : only m=0 nonzero =====
  float vr[4], vi[4];
  {
    float s0n, c0n;
    __sincosf(sg0, &s0n, &c0n);
    float2 a0 = cmul(Urow[0], make_float2(c0n, s0n));
#pragma unroll
    for (int r = 0; r < 4; ++r) { vr[r] = 0.f; vi[r] = 0.f; }
    if (lane == 0) { vr[0] = a0.x; vi[0] = a0.y; }
  }
  const float2* stab = &seltab[s * 64];

  // select_0 (fwd)
  sim14_fwd(vr, vi, lane, stab, 0, 1.f);
  sim14_fwd(vr, vi, lane, stab, 32, 1.f);
  // exchange X1
  {
#pragma unroll
    for (int r = 0; r < 4; ++r) xbuf[lane*17 + r*4 + s] = make_float2(vr[r], vi[r]);
    __syncthreads();
#pragma unroll
    for (int r = 0; r < 4; ++r) {
      const float2* p = &xbuf[lane*17 + r*4];
      float2 o = cmul(R1[0], p[0]);
      o = cadd(o, cmul(R1[1], p[1]));
      o = cadd(o, cmul(R1[2], p[2]));
      o = cadd(o, cmul(R1[3], p[3]));
      vr[r] = o.x; vi[r] = o.y;
    }
    __syncthreads();
  }
  // select_1 (adjoint)
  sim14_adj(vr, vi, lane, stab, 32);
  sim14_adj(vr, vi, lane, stab, 0);
  // exchange X2
  {
#pragma unroll
    for (int r = 0; r < 4; ++r) xbuf[lane*17 + r*4 + s] = make_float2(vr[r], vi[r]);
    __syncthreads();
#pragma unroll
    for (int r = 0; r < 4; ++r) {
      const float2* p = &xbuf[lane*17 + r*4];
      float2 o = cmul(R2[0], p[0]);
      o = cadd(o, cmul(R2[1], p[1]));
      o = cadd(o, cmul(R2[2], p[2]));
      o = cadd(o, cmul(R2[3], p[3]));
      vr[r] = o.x; vi[r] = o.y;
    }
    __syncthreads();
  }
  // select_2 (fwd)
  sim14_fwd(vr, vi, lane, stab, 0, 1.f);
  sim14_fwd(vr, vi, lane, stab, 32, 1.f);
  // exchange F = D3 U^
  {
#pragma unroll
    for (int r = 0; r < 4; ++r) xbuf[lane*17 + r*4 + s] = make_float2(vr[r], vi[r]);
    __syncthreads();
#pragma unroll
    for (int r = 0; r < 4; ++r) {
      const float2* p = &xbuf[lane*17 + r*4];
      float2 o = cmul(RF[0], p[0]);
      o = cadd(o, cmul(RF[1], p[1]));
      o = cadd(o, cmul(RF[2], p[2]));
      o = cadd(o, cmul(RF[3], p[3]));
      vr[r] = o.x; vi[r] = o.y;
    }
    __syncthreads();
  }
  // final sim14 layer with qff angles (uniform across s)
  sim14_fwd(vr, vi, lane, qtab, 0, 1.f);

  // ===== Phase D: dump (wave-local), observables =====
  *(float4*)&dumpR[s][lane*4] = make_float4(vr[0], vr[1], vr[2], vr[3]);
  *(float4*)&dumpI[s][lane*4] = make_float4(vi[0], vi[1], vi[2], vi[3]);
  // same-wave LDS RAW: ordered by lgkmcnt, no barrier needed

#pragma unroll
  for (int w = 0; w < NOBS; ++w) {
    const int pb = 6 - w;  // wires (w, w+1) -> bits (7-w, 6-w) of m
    int g = lane;
    int ib = ((g >> pb) << (pb + 2)) | (g & ((1 << pb) - 1));
    float xr[4], xi[4];
#pragma unroll
    for (int i = 0; i < 4; ++i) { xr[i] = dumpR[s][ib + (i << pb)]; xi[i] = dumpI[s][ib + (i << pb)]; }
    float a = hdc[w][0] * (xr[0]*xr[0] + xi[0]*xi[0])
            + hdc[w][1] * (xr[1]*xr[1] + xi[1]*xi[1])
            + hdc[w][2] * (xr[2]*xr[2] + xi[2]*xi[2]);
    const int oi[6] = {1, 2, 2, 3, 3, 3};
    const int oj[6] = {0, 0, 1, 0, 1, 2};
#pragma unroll
    for (int k2 = 0; k2 < 6; ++k2) {
      int i = oi[k2], j = oj[k2];
      float rr = xr[i]*xr[j] + xi[i]*xi[j];   // Re(conj(v_i) v_j)
      float ii = xr[i]*xi[j] - xi[i]*xr[j];   // Im(conj(v_i) v_j)
      a += 2.f * (hxc[w][k2]*rr - hyc[w][k2]*ii);
    }
    a += __shfl_xor(a, 32, 64);
    a += __shfl_xor(a, 16, 64);
    a += __shfl_xor(a, 8, 64);
    a += __shfl_xor(a, 4, 64);
    a += lane_xor<2>(a);
    a += lane_xor<1>(a);
    if (lane == 0) redbuf[w][s] = a;
  }
  __syncthreads();

  // ===== Phase E: head =====
  if (tid < 128) {
    float acc = shb[tid];
#pragma unroll
    for (int w = 0; w < NOBS; ++w) {
      float ev = redbuf[w][0] + redbuf[w][1] + redbuf[w][2] + redbuf[w][3];
      acc += ev * shw[tid*NOBS + w];
    }
    out[b * 128 + tid] = acc;
  }
}

extern "C" void kernel_launch(void* const* d_in, const int* in_sizes, int n_in,
                              void* d_out, int out_size, void* d_ws, size_t ws_size,
                              hipStream_t stream) {
  (void)n_in; (void)out_size; (void)d_ws; (void)ws_size;
  const float* z_t    = (const float*)d_in[0];
  const float* t      = (const float*)d_in[1];
  const float* te_w1  = (const float*)d_in[2];
  const float* te_b1  = (const float*)d_in[3];
  const float* te_w2  = (const float*)d_in[4];
  const float* te_b2  = (const float*)d_in[5];
  const float* ip_w1  = (const float*)d_in[6];
  const float* ip_b1  = (const float*)d_in[7];
  const float* ip_w2  = (const float*)d_in[8];
  const float* ip_b2  = (const float*)d_in[9];
  const float* prep_p = (const float*)d_in[10];
  const float* sig    = (const float*)d_in[11];
  const float* qff    = (const float*)d_in[12];
  const float* A_obs  = (const float*)d_in[13];
  const float* B_obs  = (const float*)d_in[14];
  const float* D_obs  = (const float*)d_in[15];
  const float* head_w = (const float*)d_in[16];
  const float* head_b = (const float*)d_in[17];
  float* out = (float*)d_out;

  int B = in_sizes[1];  // t is (B,)
  qsvt_kernel<<<B, 256, 0, stream>>>(
      z_t, t, te_w1, te_b1, te_w2, te_b2, ip_w1, ip_b1, ip_w2, ip_b2,
      prep_p, sig, qff, A_obs, B_obs, D_obs, head_w, head_b, out);
}

// Round 6
// 128.768 us; speedup vs baseline: 1.6542x; 1.0005x over previous
//
#include <hip/hip_runtime.h>
#include <math.h>

#define NOBS 7
#define TWO_PI_F 6.283185307179586f
#define PI_F 3.14159265358979f

// Per-wave state layout: wave s (of 4) holds the 256 main-register amplitudes
// for ancilla value s. Within the wave: main index m (8 bits, wire w -> bit 7-w),
// m = lane*4 + r : lane bits = wires 0..5 (lane bit 5-w), reg bits r[1]=wire6, r[0]=wire7.

constexpr int REG_MASK(int w)  { return w==6 ? 2 : w==7 ? 1 : 0; }
constexpr int LANE_MASK(int w) { return w<=5 ? (1 << (5-w)) : 0; }

// ---- VALU-only cross-lane xor exchange ----
// masks 1,2: single DPP quad_perm. mask 4 = xor3∘xor7 (2 DPP). mask 8 = xor7∘xor15 (2 DPP).
// masks 16,32: gfx950 permlane*_swap with both operands = x; outputs sum to x+partner
// independent of swap orientation -> partner = (r0+r1)-x (orientation-proof).
template<int LM>
__device__ __forceinline__ float lane_partner(float x) {
  if constexpr (LM == 1) {
    return __int_as_float(__builtin_amdgcn_mov_dpp(__float_as_int(x), 0xB1, 0xF, 0xF, true));
  } else if constexpr (LM == 2) {
    return __int_as_float(__builtin_amdgcn_mov_dpp(__float_as_int(x), 0x4E, 0xF, 0xF, true));
  } else if constexpr (LM == 4) {
    int a = __builtin_amdgcn_mov_dpp(__float_as_int(x), 0x1B, 0xF, 0xF, true);   // xor3
    return __int_as_float(__builtin_amdgcn_mov_dpp(a, 0x141, 0xF, 0xF, true));   // xor7 -> net xor4
  } else if constexpr (LM == 8) {
    int a = __builtin_amdgcn_mov_dpp(__float_as_int(x), 0x141, 0xF, 0xF, true);  // xor7
    return __int_as_float(__builtin_amdgcn_mov_dpp(a, 0x140, 0xF, 0xF, true));   // xor15 -> net xor8
  } else if constexpr (LM == 16) {
#if __has_builtin(__builtin_amdgcn_permlane16_swap)
    unsigned xu = __float_as_uint(x);
    auto r = __builtin_amdgcn_permlane16_swap(xu, xu, false, false);
    return (__uint_as_float(r[0]) + __uint_as_float(r[1])) - x;
#else
    return __shfl_xor(x, 16, 64);
#endif
  } else {
#if __has_builtin(__builtin_amdgcn_permlane32_swap)
    unsigned xu = __float_as_uint(x);
    auto r = __builtin_amdgcn_permlane32_swap(xu, xu, false, false);
    return (__uint_as_float(r[0]) + __uint_as_float(r[1])) - x;
#else
    return __shfl_xor(x, 32, 64);
#endif
  }
}

// x + partner (exact for 16/32 via dual-output swap; used in reductions)
template<int LM>
__device__ __forceinline__ float xor_sum(float x) {
  if constexpr (LM == 16) {
#if __has_builtin(__builtin_amdgcn_permlane16_swap)
    unsigned xu = __float_as_uint(x);
    auto r = __builtin_amdgcn_permlane16_swap(xu, xu, false, false);
    return __uint_as_float(r[0]) + __uint_as_float(r[1]);
#else
    return x + __shfl_xor(x, 16, 64);
#endif
  } else if constexpr (LM == 32) {
#if __has_builtin(__builtin_amdgcn_permlane32_swap)
    unsigned xu = __float_as_uint(x);
    auto r = __builtin_amdgcn_permlane32_swap(xu, xu, false, false);
    return __uint_as_float(r[0]) + __uint_as_float(r[1]);
#else
    return x + __shfl_xor(x, 32, 64);
#endif
  } else {
    return x + lane_partner<LM>(x);
  }
}

__device__ __forceinline__ float rdlane(float v, int idx) {
  return __int_as_float(__builtin_amdgcn_readlane(__float_as_int(v), idx));
}

__device__ __forceinline__ float2 cmul(float2 a, float2 b) {
  return make_float2(a.x*b.x - a.y*b.y, a.x*b.y + a.y*b.x);
}
__device__ __forceinline__ float2 cmulc(float2 a, float2 b) {  // a * conj(b)
  return make_float2(a.x*b.x + a.y*b.y, a.y*b.x - a.x*b.y);
}
__device__ __forceinline__ float2 cadd(float2 a, float2 b) {
  return make_float2(a.x + b.x, a.y + b.y);
}

// ---------------- in-register gate helpers (4 amps/lane) ----------------
// Angles live in VGPRs: lane g of (creg,sreg) holds gate g's (cos,sin) of theta/2.

template<int W>
__device__ __forceinline__ void ry_gate(float* vr, float* vi, int lane,
                                        float creg, float sreg, int idx, float sg)
{
  float c = rdlane(creg, idx);
  float s = sg * rdlane(sreg, idx);
  if constexpr (REG_MASK(W) != 0) {
    constexpr int m = REG_MASK(W);
#pragma unroll
    for (int r = 0; r < 4; ++r) {
      if (r & m) continue;
      const int r1 = r | m;
      float a0 = vr[r], a1 = vr[r1];
      vr[r]  = c*a0 - s*a1;  vr[r1] = s*a0 + c*a1;
      float b0 = vi[r], b1 = vi[r1];
      vi[r]  = c*b0 - s*b1;  vi[r1] = s*b0 + c*b1;
    }
  } else {
    constexpr int LM = LANE_MASK(W);
    const float ls = (lane & LM) ? s : -s;
#pragma unroll
    for (int r = 0; r < 4; ++r) {
      float pr = lane_partner<LM>(vr[r]);
      float pi = lane_partner<LM>(vi[r]);
      vr[r] = c*vr[r] + ls*pr;
      vi[r] = c*vi[r] + ls*pi;
    }
  }
}

template<int WC, int WT>
__device__ __forceinline__ void crx_gate(float* vr, float* vi, int lane,
                                         float creg, float sreg, int idx, float sg)
{
  float c = rdlane(creg, idx);
  float s = sg * rdlane(sreg, idx);
  constexpr int MC = REG_MASK(WC), LC = LANE_MASK(WC);
  constexpr int MT = REG_MASK(WT), LT = LANE_MASK(WT);
  if constexpr (MC != 0 && MT != 0) {
#pragma unroll
    for (int r = 0; r < 4; ++r) {
      if (!(r & MC) || (r & MT)) continue;
      const int r1 = r | MT;
      float xr = vr[r], xi = vi[r], yr = vr[r1], yi = vi[r1];
      vr[r]  = c*xr + s*yi;  vi[r]  = c*xi - s*yr;
      vr[r1] = c*yr + s*xi;  vi[r1] = c*yi - s*xr;
    }
  } else if constexpr (MC != 0) {  // control reg-local, target lane bit
#pragma unroll
    for (int r = 0; r < 4; ++r) {
      if (!(r & MC)) continue;
      float pr = lane_partner<LT>(vr[r]);
      float pi = lane_partner<LT>(vi[r]);
      vr[r] = c*vr[r] + s*pi;
      vi[r] = c*vi[r] - s*pr;
    }
  } else if constexpr (MT != 0) {  // control lane bit, target reg-local
    const bool act = (lane & LC) != 0;
#pragma unroll
    for (int r = 0; r < 4; ++r) {
      if (r & MT) continue;
      const int r1 = r | MT;
      float xr = vr[r], xi = vi[r], yr = vr[r1], yi = vi[r1];
      float nxr = c*xr + s*yi, nxi = c*xi - s*yr;
      float nyr = c*yr + s*xi, nyi = c*yi - s*xr;
      vr[r]  = act ? nxr : xr;  vi[r]  = act ? nxi : xi;
      vr[r1] = act ? nyr : yr;  vi[r1] = act ? nyi : yi;
    }
  } else {  // both lane bits
    const bool act = (lane & LC) != 0;
#pragma unroll
    for (int r = 0; r < 4; ++r) {
      float pr = lane_partner<LT>(vr[r]);
      float pi = lane_partner<LT>(vi[r]);
      float nr = c*vr[r] + s*pi;
      float ni = c*vi[r] - s*pr;
      vr[r] = act ? nr : vr[r];
      vi[r] = act ? ni : vi[r];
    }
  }
}

// ---------------- sim14 layers (32 gates each) ----------------

__device__ __forceinline__ void sim14_fwd(float* vr, float* vi, int lane,
                                          float ct, float st, int off, float sg)
{
  ry_gate<0>(vr,vi,lane,ct,st,off+0,sg);  ry_gate<1>(vr,vi,lane,ct,st,off+1,sg);
  ry_gate<2>(vr,vi,lane,ct,st,off+2,sg);  ry_gate<3>(vr,vi,lane,ct,st,off+3,sg);
  ry_gate<4>(vr,vi,lane,ct,st,off+4,sg);  ry_gate<5>(vr,vi,lane,ct,st,off+5,sg);
  ry_gate<6>(vr,vi,lane,ct,st,off+6,sg);  ry_gate<7>(vr,vi,lane,ct,st,off+7,sg);
  crx_gate<7,0>(vr,vi,lane,ct,st,off+8,sg);  crx_gate<6,7>(vr,vi,lane,ct,st,off+9,sg);
  crx_gate<5,6>(vr,vi,lane,ct,st,off+10,sg); crx_gate<4,5>(vr,vi,lane,ct,st,off+11,sg);
  crx_gate<3,4>(vr,vi,lane,ct,st,off+12,sg); crx_gate<2,3>(vr,vi,lane,ct,st,off+13,sg);
  crx_gate<1,2>(vr,vi,lane,ct,st,off+14,sg); crx_gate<0,1>(vr,vi,lane,ct,st,off+15,sg);
  ry_gate<0>(vr,vi,lane,ct,st,off+16,sg); ry_gate<1>(vr,vi,lane,ct,st,off+17,sg);
  ry_gate<2>(vr,vi,lane,ct,st,off+18,sg); ry_gate<3>(vr,vi,lane,ct,st,off+19,sg);
  ry_gate<4>(vr,vi,lane,ct,st,off+20,sg); ry_gate<5>(vr,vi,lane,ct,st,off+21,sg);
  ry_gate<6>(vr,vi,lane,ct,st,off+22,sg); ry_gate<7>(vr,vi,lane,ct,st,off+23,sg);
  crx_gate<7,6>(vr,vi,lane,ct,st,off+24,sg); crx_gate<0,7>(vr,vi,lane,ct,st,off+25,sg);
  crx_gate<1,0>(vr,vi,lane,ct,st,off+26,sg); crx_gate<2,1>(vr,vi,lane,ct,st,off+27,sg);
  crx_gate<3,2>(vr,vi,lane,ct,st,off+28,sg); crx_gate<4,3>(vr,vi,lane,ct,st,off+29,sg);
  crx_gate<5,4>(vr,vi,lane,ct,st,off+30,sg); crx_gate<6,5>(vr,vi,lane,ct,st,off+31,sg);
}

__device__ __forceinline__ void sim14_adj(float* vr, float* vi, int lane,
                                          float ct, float st, int off)
{
  const float sg = -1.f;
  crx_gate<6,5>(vr,vi,lane,ct,st,off+31,sg); crx_gate<5,4>(vr,vi,lane,ct,st,off+30,sg);
  crx_gate<4,3>(vr,vi,lane,ct,st,off+29,sg); crx_gate<3,2>(vr,vi,lane,ct,st,off+28,sg);
  crx_gate<2,1>(vr,vi,lane,ct,st,off+27,sg); crx_gate<1,0>(vr,vi,lane,ct,st,off+26,sg);
  crx_gate<0,7>(vr,vi,lane,ct,st,off+25,sg); crx_gate<7,6>(vr,vi,lane,ct,st,off+24,sg);
  ry_gate<7>(vr,vi,lane,ct,st,off+23,sg); ry_gate<6>(vr,vi,lane,ct,st,off+22,sg);
  ry_gate<5>(vr,vi,lane,ct,st,off+21,sg); ry_gate<4>(vr,vi,lane,ct,st,off+20,sg);
  ry_gate<3>(vr,vi,lane,ct,st,off+19,sg); ry_gate<2>(vr,vi,lane,ct,st,off+18,sg);
  ry_gate<1>(vr,vi,lane,ct,st,off+17,sg); ry_gate<0>(vr,vi,lane,ct,st,off+16,sg);
  crx_gate<0,1>(vr,vi,lane,ct,st,off+15,sg); crx_gate<1,2>(vr,vi,lane,ct,st,off+14,sg);
  crx_gate<2,3>(vr,vi,lane,ct,st,off+13,sg); crx_gate<3,4>(vr,vi,lane,ct,st,off+12,sg);
  crx_gate<4,5>(vr,vi,lane,ct,st,off+11,sg); crx_gate<5,6>(vr,vi,lane,ct,st,off+10,sg);
  crx_gate<6,7>(vr,vi,lane,ct,st,off+9,sg);  crx_gate<7,0>(vr,vi,lane,ct,st,off+8,sg);
  ry_gate<7>(vr,vi,lane,ct,st,off+7,sg); ry_gate<6>(vr,vi,lane,ct,st,off+6,sg);
  ry_gate<5>(vr,vi,lane,ct,st,off+5,sg); ry_gate<4>(vr,vi,lane,ct,st,off+4,sg);
  ry_gate<3>(vr,vi,lane,ct,st,off+3,sg); ry_gate<2>(vr,vi,lane,ct,st,off+2,sg);
  ry_gate<1>(vr,vi,lane,ct,st,off+1,sg); ry_gate<0>(vr,vi,lane,ct,st,off+0,sg);
}

// ---------------- cooperative-row MLP layer ----------------
// 8 lanes per output row; coalesced 128B segments; VALU-only reduction.
// MODE: 0 = silu->yl, 1 = raw->yl, 2 = seltab ((float2*)yl)

template<int IN, int NP, int MODE>
__device__ __forceinline__ void mlp_layer(const float* __restrict__ W,
    const float* __restrict__ bias, const float* xl, float* yl,
    int rbase, int lane)
{
  const int sub = lane & 7;
  const int g   = lane >> 3;
#pragma unroll
  for (int p = 0; p < NP; ++p) {
    const int row = rbase + p * 8 + g;
    const float4* w4 = (const float4*)(W + row * IN) + sub;
    const float4* x4 = (const float4*)xl + sub;
    float acc = 0.f;
#pragma unroll
    for (int it = 0; it < IN / 32; ++it) {
      float4 w = w4[it * 8], e = x4[it * 8];
      acc += w.x*e.x + w.y*e.y + w.z*e.z + w.w*e.w;
    }
    acc = xor_sum<1>(acc);
    acc = xor_sum<2>(acc);
    acc = xor_sum<4>(acc);
    if (sub == 0) {
      float a = acc + bias[row];
      if constexpr (MODE == 0) {
        yl[row] = a / (1.f + __expf(-a));
      } else if constexpr (MODE == 1) {
        yl[row] = a;
      } else {
        float th = PI_F / (1.f + __expf(-a));   // theta/2 = pi * sigmoid(a)
        float sn, cn;
        __sincosf(th, &sn, &cn);
        ((float2*)yl)[row] = make_float2(cn, sn);
      }
    }
  }
}

// ---------------- main kernel: 256 threads = 4 waves, one batch elem/block ----------------

__global__ __launch_bounds__(256) void qsvt_kernel(
    const float* __restrict__ z_t, const float* __restrict__ t,
    const float* __restrict__ te_w1, const float* __restrict__ te_b1,
    const float* __restrict__ te_w2, const float* __restrict__ te_b2,
    const float* __restrict__ ip_w1, const float* __restrict__ ip_b1,
    const float* __restrict__ ip_w2, const float* __restrict__ ip_b2,
    const float* __restrict__ prep_p, const float* __restrict__ sig,
    const float* __restrict__ qff, const float* __restrict__ A_obs,
    const float* __restrict__ B_obs, const float* __restrict__ D_obs,
    const float* __restrict__ head_w, const float* __restrict__ head_b,
    float* __restrict__ out)
{
  __shared__ __align__(16) float emb[128];
  __shared__ __align__(16) float y1[128];
  __shared__ __align__(16) float hbuf[256];
  __shared__ __align__(16) float h1[256];
  __shared__ __align__(16) float2 seltab[256];  // [s*64+g] -> (cos(th/2), sin(th/2))
  __shared__ __align__(16) float2 qtab[32];
  __shared__ __align__(16) float2 xbuf[64*17];  // exchange: lane region stride 17 float2
  __shared__ __align__(16) float dumpR[4][256];
  __shared__ __align__(16) float dumpI[4][256];
  __shared__ float redbuf[NOBS][4];
  __shared__ float hdc[NOBS][3], hxc[NOBS][6], hyc[NOBS][6];
  __shared__ __align__(16) float shw[128*NOBS];
  __shared__ __align__(16) float shb[128];

  const int tid  = threadIdx.x;
  const int lane = tid & 63;
  const int s    = tid >> 6;   // wave id == ancilla value
  const int b    = blockIdx.x;

  // ===== Phase A: MLP (cooperative rows) =====
  if (tid < 128) {
    int j = tid & 63;
    float fr = __expf(-9.210340371976184f * (float)j / 64.f);  // exp(-ln(1e4)*j/64)
    float arg = t[b] * fr;
    float sn, cn;
    __sincosf(arg, &sn, &cn);
    emb[tid] = (tid < 64) ? cn : sn;
  } else if (tid < 160) {
    int j = tid - 128;
    float sn, cn;
    __sincosf(0.5f * qff[j], &sn, &cn);
    qtab[j] = make_float2(cn, sn);
  }
  __syncthreads();

  mlp_layer<128, 4, 0>(te_w1, te_b1, emb, y1, s * 32, lane);
  if (tid < 128) hbuf[tid] = z_t[b * 128 + tid];
  __syncthreads();

  mlp_layer<128, 4, 1>(te_w2, te_b2, y1, hbuf + 128, s * 32, lane);
  __syncthreads();

  mlp_layer<256, 8, 0>(ip_w1, ip_b1, hbuf, h1, s * 64, lane);
  __syncthreads();

  mlp_layer<256, 8, 2>(ip_w2, ip_b2, h1, (float*)seltab, s * 64, lane);

  // prefetch observable + head coefficients into LDS (off the tail path)
  if (tid < NOBS * 6)      { hxc[tid/6][tid%6] = A_obs[tid]; hyc[tid/6][tid%6] = B_obs[tid]; }
  else if (tid >= 64 && tid < 64 + NOBS*3) { int q = tid - 64; hdc[q/3][q%3] = 2.f * D_obs[(q/3)*4 + (q%3) + 1]; }
#pragma unroll
  for (int i = tid; i < 128*NOBS; i += 256) shw[i] = head_w[i];
  if (tid < 128) shb[tid] = head_b[tid];

  // ===== Phase B: per-thread 4x4 ancilla matrices (registers) =====
  float2 Ga[2][2][2], Gb[2][2][2];
#pragma unroll
  for (int ly = 0; ly < 2; ++ly) {
#pragma unroll
    for (int qi = 0; qi < 2; ++qi) {
      float y = prep_p[ly*4 + qi*2 + 0], z = prep_p[ly*4 + qi*2 + 1];
      float cy, sy, cz, sz;
      __sincosf(0.5f*y, &sy, &cy);
      __sincosf(0.5f*z, &sz, &cz);
      float2 g00 = make_float2( cy*cz, -cy*sz);
      float2 g01 = make_float2(-sy*cz,  sy*sz);
      float2 g10 = make_float2( sy*cz,  sy*sz);
      float2 g11 = make_float2( cy*cz,  cy*sz);
      if (qi == 0) { Ga[ly][0][0]=g00; Ga[ly][0][1]=g01; Ga[ly][1][0]=g10; Ga[ly][1][1]=g11; }
      else         { Gb[ly][0][0]=g00; Gb[ly][0][1]=g01; Gb[ly][1][0]=g10; Gb[ly][1][1]=g11; }
    }
  }
  float2 M[2][4][4];
#pragma unroll
  for (int ly = 0; ly < 2; ++ly) {
    float2 T[4][4];
#pragma unroll
    for (int i = 0; i < 4; ++i)
#pragma unroll
      for (int j = 0; j < 4; ++j)
        T[i][j] = cmul(Ga[ly][i>>1][j>>1], Gb[ly][i&1][j&1]);
#pragma unroll
    for (int j = 0; j < 4; ++j) {
      M[ly][0][j] = T[0][j]; M[ly][1][j] = T[1][j];
      M[ly][2][j] = T[3][j]; M[ly][3][j] = T[2][j];
    }
  }
  float2 U[4][4];
#pragma unroll
  for (int i = 0; i < 4; ++i)
#pragma unroll
    for (int j = 0; j < 4; ++j) {
      float2 acc = make_float2(0.f, 0.f);
#pragma unroll
      for (int kk = 0; kk < 4; ++kk) acc = cadd(acc, cmul(M[1][i][kk], M[0][kk][j]));
      U[i][j] = acc;
    }
  float2 Urow[4], Ucol[4];
#pragma unroll
  for (int j = 0; j < 4; ++j) {
    Urow[j] = s==0 ? U[0][j] : s==1 ? U[1][j] : s==2 ? U[2][j] : U[3][j];
    Ucol[j] = s==0 ? U[j][0] : s==1 ? U[j][1] : s==2 ? U[j][2] : U[j][3];
  }
  float sg0 = sig[0], sg1 = sig[1], sg2 = sig[2], sg3 = sig[3];
  float c1, s1v, c2, s2v, c3, s3v;
  __sincosf(sg1, &s1v, &c1);
  __sincosf(sg2, &s2v, &c2);
  __sincosf(sg3, &s3v, &c3);
  float2 R1[4], R2[4], RF[4];
  {
    float s3s = (s == 0) ? s3v : -s3v;
    float2 d3 = make_float2(c3, s3s);
#pragma unroll
    for (int sp = 0; sp < 4; ++sp) {
      float2 a1 = make_float2(0.f, 0.f), a2 = make_float2(0.f, 0.f);
#pragma unroll
      for (int j = 0; j < 4; ++j) {
        float2 uspj = sp==0 ? U[0][j] : sp==1 ? U[1][j] : sp==2 ? U[2][j] : U[3][j];
        float2 tt = cmulc(Urow[j], uspj);            // U[s][j] * conj(U[sp][j])
        float sj = (j == 0) ? 1.f : -1.f;
        a1 = cadd(a1, cmul(tt, make_float2(c1, sj*s1v)));
        a2 = cadd(a2, cmul(tt, make_float2(c2, sj*s2v)));
      }
      R1[sp] = a1; R2[sp] = a2;
      RF[sp] = cmul(d3, make_float2(Ucol[sp].x, -Ucol[sp].y));  // D3[s]*conj(U[sp][s])
    }
  }
  __syncthreads();  // seltab/qtab/coefs visible to all waves

  // pull this wave's angle tables into registers (lane g <-> gate g)
  float2 mycs = seltab[(s << 6) | lane];
  float selc = mycs.x, sels = mycs.y;
  float2 myq = qtab[lane & 31];
  float qc = myq.x, qs = myq.y;

  // ===== Phase C: circuit. init = U * D0 * |0..0> : only m=0 nonzero =====
  float vr[4], vi[4];
  {
    float s0n, c0n;
    __sincosf(sg0, &s0n, &c0n);
    float2 a0 = cmul(Urow[0], make_float2(c0n, s0n));
#pragma unroll
    for (int r = 0; r < 4; ++r) { vr[r] = 0.f; vi[r] = 0.f; }
    if (lane == 0) { vr[0] = a0.x; vi[0] = a0.y; }
  }

  // select_0 (fwd)
  sim14_fwd(vr, vi, lane, selc, sels, 0, 1.f);
  sim14_fwd(vr, vi, lane, selc, sels, 32, 1.f);
  // exchange X1
  {
#pragma unroll
    for (int r = 0; r < 4; ++r) xbuf[lane*17 + r*4 + s] = make_float2(vr[r], vi[r]);
    __syncthreads();
#pragma unroll
    for (int r = 0; r < 4; ++r) {
      const float2* p = &xbuf[lane*17 + r*4];
      float2 o = cmul(R1[0], p[0]);
      o = cadd(o, cmul(R1[1], p[1]));
      o = cadd(o, cmul(R1[2], p[2]));
      o = cadd(o, cmul(R1[3], p[3]));
      vr[r] = o.x; vi[r] = o.y;
    }
    __syncthreads();
  }
  // select_1 (adjoint)
  sim14_adj(vr, vi, lane, selc, sels, 32);
  sim14_adj(vr, vi, lane, selc, sels, 0);
  // exchange X2
  {
#pragma unroll
    for (int r = 0; r < 4; ++r) xbuf[lane*17 + r*4 + s] = make_float2(vr[r], vi[r]);
    __syncthreads();
#pragma unroll
    for (int r = 0; r < 4; ++r) {
      const float2* p = &xbuf[lane*17 + r*4];
      float2 o = cmul(R2[0], p[0]);
      o = cadd(o, cmul(R2[1], p[1]));
      o = cadd(o, cmul(R2[2], p[2]));
      o = cadd(o, cmul(R2[3], p[3]));
      vr[r] = o.x; vi[r] = o.y;
    }
    __syncthreads();
  }
  // select_2 (fwd)
  sim14_fwd(vr, vi, lane, selc, sels, 0, 1.f);
  sim14_fwd(vr, vi, lane, selc, sels, 32, 1.f);
  // exchange F = D3 U^
  {
#pragma unroll
    for (int r = 0; r < 4; ++r) xbuf[lane*17 + r*4 + s] = make_float2(vr[r], vi[r]);
    __syncthreads();
#pragma unroll
    for (int r = 0; r < 4; ++r) {
      const float2* p = &xbuf[lane*17 + r*4];
      float2 o = cmul(RF[0], p[0]);
      o = cadd(o, cmul(RF[1], p[1]));
      o = cadd(o, cmul(RF[2], p[2]));
      o = cadd(o, cmul(RF[3], p[3]));
      vr[r] = o.x; vi[r] = o.y;
    }
    __syncthreads();
  }
  // final sim14 layer with qff angles (uniform across s)
  sim14_fwd(vr, vi, lane, qc, qs, 0, 1.f);

  // ===== Phase D: dump (wave-local), observables =====
  *(float4*)&dumpR[s][lane*4] = make_float4(vr[0], vr[1], vr[2], vr[3]);
  *(float4*)&dumpI[s][lane*4] = make_float4(vi[0], vi[1], vi[2], vi[3]);
  // same-wave LDS RAW: ordered by lgkmcnt, no barrier needed

#pragma unroll
  for (int w = 0; w < NOBS; ++w) {
    const int pb = 6 - w;  // wires (w, w+1) -> bits (7-w, 6-w) of m
    int g = lane;
    int ib = ((g >> pb) << (pb + 2)) | (g & ((1 << pb) - 1));
    float xr[4], xi[4];
#pragma unroll
    for (int i = 0; i < 4; ++i) { xr[i] = dumpR[s][ib + (i << pb)]; xi[i] = dumpI[s][ib + (i << pb)]; }
    float a = hdc[w][0] * (xr[0]*xr[0] + xi[0]*xi[0])
            + hdc[w][1] * (xr[1]*xr[1] + xi[1]*xi[1])
            + hdc[w][2] * (xr[2]*xr[2] + xi[2]*xi[2]);
    const int oi[6] = {1, 2, 2, 3, 3, 3};
    const int oj[6] = {0, 0, 1, 0, 1, 2};
#pragma unroll
    for (int k2 = 0; k2 < 6; ++k2) {
      int i = oi[k2], j = oj[k2];
      float rr = xr[i]*xr[j] + xi[i]*xi[j];   // Re(conj(v_i) v_j)
      float ii = xr[i]*xi[j] - xi[i]*xr[j];   // Im(conj(v_i) v_j)
      a += 2.f * (hxc[w][k2]*rr - hyc[w][k2]*ii);
    }
    a = xor_sum<32>(a);
    a = xor_sum<16>(a);
    a = xor_sum<8>(a);
    a = xor_sum<4>(a);
    a = xor_sum<2>(a);
    a = xor_sum<1>(a);
    if (lane == 0) redbuf[w][s] = a;
  }
  __syncthreads();

  // ===== Phase E: head =====
  if (tid < 128) {
    float acc = shb[tid];
#pragma unroll
    for (int w = 0; w < NOBS; ++w) {
      float ev = redbuf[w][0] + redbuf[w][1] + redbuf[w][2] + redbuf[w][3];
      acc += ev * shw[tid*NOBS + w];
    }
    out[b * 128 + tid] = acc;
  }
}

extern "C" void kernel_launch(void* const* d_in, const int* in_sizes, int n_in,
                              void* d_out, int out_size, void* d_ws, size_t ws_size,
                              hipStream_t stream) {
  (void)n_in; (void)out_size; (void)d_ws; (void)ws_size;
  const float* z_t    = (const float*)d_in[0];
  const float* t      = (const float*)d_in[1];
  const float* te_w1  = (const float*)d_in[2];
  const float* te_b1  = (const float*)d_in[3];
  const float* te_w2  = (const float*)d_in[4];
  const float* te_b2  = (const float*)d_in[5];
  const float* ip_w1  = (const float*)d_in[6];
  const float* ip_b1  = (const float*)d_in[7];
  const float* ip_w2  = (const float*)d_in[8];
  const float* ip_b2  = (const float*)d_in[9];
  const float* prep_p = (const float*)d_in[10];
  const float* sig    = (const float*)d_in[11];
  const float* qff    = (const float*)d_in[12];
  const float* A_obs  = (const float*)d_in[13];
  const float* B_obs  = (const float*)d_in[14];
  const float* D_obs  = (const float*)d_in[15];
  const float* head_w = (const float*)d_in[16];
  const float* head_b = (const float*)d_in[17];
  float* out = (float*)d_out;

  int B = in_sizes[1];  // t is (B,)
  qsvt_kernel<<<B, 256, 0, stream>>>(
      z_t, t, te_w1, te_b1, te_w2, te_b2, ip_w1, ip_b1, ip_w2, ip_b2,
      prep_p, sig, qff, A_obs, B_obs, D_obs, head_w, head_b, out);
}

// Round 7
// 127.168 us; speedup vs baseline: 1.6750x; 1.0126x over previous
//
#include <hip/hip_runtime.h>
#include <math.h>

#define NOBS 7
#define PI_F 3.14159265358979f

// ---- Layout ----
// Block = 512 threads = 8 waves. Wave wv = h*4 + s : s = ancilla value (0..3),
// h = wire-6 value (0..1). Each wave holds 128 main-register amplitudes:
// main index m (8 bits, wire w -> bit 7-w) = (lane<<2) | (h<<1) | r,
// lane bits = wires 0..5 (lane bit 5-w), h = wire6, r (reg, 2 amps/lane) = wire7.

// ---- VALU-only cross-lane xor exchange (round-6, verified) ----
template<int LM>
__device__ __forceinline__ float lane_partner(float x) {
  if constexpr (LM == 1) {
    return __int_as_float(__builtin_amdgcn_mov_dpp(__float_as_int(x), 0xB1, 0xF, 0xF, true));
  } else if constexpr (LM == 2) {
    return __int_as_float(__builtin_amdgcn_mov_dpp(__float_as_int(x), 0x4E, 0xF, 0xF, true));
  } else if constexpr (LM == 4) {
    int a = __builtin_amdgcn_mov_dpp(__float_as_int(x), 0x1B, 0xF, 0xF, true);   // xor3
    return __int_as_float(__builtin_amdgcn_mov_dpp(a, 0x141, 0xF, 0xF, true));   // xor7 -> net xor4
  } else if constexpr (LM == 8) {
    int a = __builtin_amdgcn_mov_dpp(__float_as_int(x), 0x141, 0xF, 0xF, true);  // xor7
    return __int_as_float(__builtin_amdgcn_mov_dpp(a, 0x140, 0xF, 0xF, true));   // xor15 -> net xor8
  } else if constexpr (LM == 16) {
#if __has_builtin(__builtin_amdgcn_permlane16_swap)
    unsigned xu = __float_as_uint(x);
    auto r = __builtin_amdgcn_permlane16_swap(xu, xu, false, false);
    return (__uint_as_float(r[0]) + __uint_as_float(r[1])) - x;
#else
    return __shfl_xor(x, 16, 64);
#endif
  } else {
#if __has_builtin(__builtin_amdgcn_permlane32_swap)
    unsigned xu = __float_as_uint(x);
    auto r = __builtin_amdgcn_permlane32_swap(xu, xu, false, false);
    return (__uint_as_float(r[0]) + __uint_as_float(r[1])) - x;
#else
    return __shfl_xor(x, 32, 64);
#endif
  }
}

template<int LM>
__device__ __forceinline__ float xor_sum(float x) {
  if constexpr (LM == 16) {
#if __has_builtin(__builtin_amdgcn_permlane16_swap)
    unsigned xu = __float_as_uint(x);
    auto r = __builtin_amdgcn_permlane16_swap(xu, xu, false, false);
    return __uint_as_float(r[0]) + __uint_as_float(r[1]);
#else
    return x + __shfl_xor(x, 16, 64);
#endif
  } else if constexpr (LM == 32) {
#if __has_builtin(__builtin_amdgcn_permlane32_swap)
    unsigned xu = __float_as_uint(x);
    auto r = __builtin_amdgcn_permlane32_swap(xu, xu, false, false);
    return __uint_as_float(r[0]) + __uint_as_float(r[1]);
#else
    return x + __shfl_xor(x, 32, 64);
#endif
  } else {
    return x + lane_partner<LM>(x);
  }
}

__device__ __forceinline__ float rdlane(float v, int idx) {
  return __int_as_float(__builtin_amdgcn_readlane(__float_as_int(v), idx));
}

__device__ __forceinline__ float2 cmul(float2 a, float2 b) {
  return make_float2(a.x*b.x - a.y*b.y, a.x*b.y + a.y*b.x);
}
__device__ __forceinline__ float2 cmulc(float2 a, float2 b) {  // a * conj(b)
  return make_float2(a.x*b.x + a.y*b.y, a.y*b.x - a.x*b.y);
}
__device__ __forceinline__ float2 cadd(float2 a, float2 b) {
  return make_float2(a.x + b.x, a.y + b.y);
}

// ---- circuit context ----
struct Ctx {
  float4* xw;   // [2][8][64] double-buffered wave-pair exchange
  int pp;       // buffer parity
  int wv, lane, h;
};

// exchange this wave's (vr0,vr1,vi0,vi1) with sibling wave (wv^4); 1 barrier
__device__ __forceinline__ float4 wexch(Ctx& cx, const float* vr, const float* vi) {
  float4* buf = cx.xw + cx.pp * 512;
  buf[cx.wv * 64 + cx.lane] = make_float4(vr[0], vr[1], vi[0], vi[1]);
  __syncthreads();
  float4 p = buf[(cx.wv ^ 4) * 64 + cx.lane];
  cx.pp ^= 1;
  return p;
}

// ---------------- gate helpers (2 amps/lane) ----------------

// RY wires 0..5 (lane bits)
template<int W>
__device__ __forceinline__ void ry_lane(float* vr, float* vi, Ctx& cx,
                                        float ct, float st, int idx, float sg) {
  float c = rdlane(ct, idx), s = sg * rdlane(st, idx);
  constexpr int LM = 1 << (5 - W);
  const float ls = (cx.lane & LM) ? s : -s;
#pragma unroll
  for (int r = 0; r < 2; ++r) {
    float pr = lane_partner<LM>(vr[r]);
    float pi = lane_partner<LM>(vi[r]);
    vr[r] = c*vr[r] + ls*pr;
    vi[r] = c*vi[r] + ls*pi;
  }
}

// RY wire 6 (wave-pair bit)
__device__ __forceinline__ void ry_wave6(float* vr, float* vi, Ctx& cx,
                                         float ct, float st, int idx, float sg) {
  float c = rdlane(ct, idx), s = sg * rdlane(st, idx);
  float4 P = wexch(cx, vr, vi);
  const float ls = cx.h ? s : -s;
  vr[0] = c*vr[0] + ls*P.x;  vr[1] = c*vr[1] + ls*P.y;
  vi[0] = c*vi[0] + ls*P.z;  vi[1] = c*vi[1] + ls*P.w;
}

// RY wire 7 (reg pair)
__device__ __forceinline__ void ry_reg7(float* vr, float* vi,
                                        float ct, float st, int idx, float sg) {
  float c = rdlane(ct, idx), s = sg * rdlane(st, idx);
  float a0 = vr[0], a1 = vr[1];
  vr[0] = c*a0 - s*a1;  vr[1] = s*a0 + c*a1;
  float b0 = vi[0], b1 = vi[1];
  vi[0] = c*b0 - s*b1;  vi[1] = s*b0 + c*b1;
}

// CRX lane-control, lane-target (wires C,T in 0..5)
template<int C, int T>
__device__ __forceinline__ void crx_ll(float* vr, float* vi, Ctx& cx,
                                       float ct, float st, int idx, float sg) {
  float c = rdlane(ct, idx), s = sg * rdlane(st, idx);
  constexpr int LC = 1 << (5 - C), LT = 1 << (5 - T);
  const bool act = (cx.lane & LC) != 0;
  const float cp = act ? c : 1.f, sp = act ? s : 0.f;
#pragma unroll
  for (int r = 0; r < 2; ++r) {
    float pr = lane_partner<LT>(vr[r]);
    float pi = lane_partner<LT>(vi[r]);
    vr[r] = cp*vr[r] + sp*pi;
    vi[r] = cp*vi[r] - sp*pr;
  }
}

// CRX control wire7 (r==1), target lane wire T
template<int T>
__device__ __forceinline__ void crx_7l(float* vr, float* vi, Ctx& cx,
                                       float ct, float st, int idx, float sg) {
  float c = rdlane(ct, idx), s = sg * rdlane(st, idx);
  constexpr int LT = 1 << (5 - T);
  float pr = lane_partner<LT>(vr[1]);
  float pi = lane_partner<LT>(vi[1]);
  vr[1] = c*vr[1] + s*pi;
  vi[1] = c*vi[1] - s*pr;
}

// CRX control lane wire C, target wire7 (reg pair)
template<int C>
__device__ __forceinline__ void crx_l7(float* vr, float* vi, Ctx& cx,
                                       float ct, float st, int idx, float sg) {
  float c = rdlane(ct, idx), s = sg * rdlane(st, idx);
  constexpr int LC = 1 << (5 - C);
  const bool act = (cx.lane & LC) != 0;
  const float cp = act ? c : 1.f, sp = act ? s : 0.f;
  float xr = vr[0], xi = vi[0], yr = vr[1], yi = vi[1];
  vr[0] = cp*xr + sp*yi;  vi[0] = cp*xi - sp*yr;
  vr[1] = cp*yr + sp*xi;  vi[1] = cp*yi - sp*xr;
}

// CRX control lane wire C, target wire6 (wave exchange)
template<int C>
__device__ __forceinline__ void crx_l6(float* vr, float* vi, Ctx& cx,
                                       float ct, float st, int idx, float sg) {
  float c = rdlane(ct, idx), s = sg * rdlane(st, idx);
  float4 P = wexch(cx, vr, vi);
  constexpr int LC = 1 << (5 - C);
  const bool act = (cx.lane & LC) != 0;
  const float cp = act ? c : 1.f, sp = act ? s : 0.f;
  vr[0] = cp*vr[0] + sp*P.z;  vi[0] = cp*vi[0] - sp*P.x;
  vr[1] = cp*vr[1] + sp*P.w;  vi[1] = cp*vi[1] - sp*P.y;
}

// CRX control wire7 (r==1), target wire6 (wave exchange)
__device__ __forceinline__ void crx_76(float* vr, float* vi, Ctx& cx,
                                       float ct, float st, int idx, float sg) {
  float c = rdlane(ct, idx), s = sg * rdlane(st, idx);
  float4 P = wexch(cx, vr, vi);
  vr[1] = c*vr[1] + s*P.w;
  vi[1] = c*vi[1] - s*P.y;
}

// CRX control wire6 (h==1 waves), target wire7 (reg pair)
__device__ __forceinline__ void crx_67(float* vr, float* vi, Ctx& cx,
                                       float ct, float st, int idx, float sg) {
  if (cx.h) {
    float c = rdlane(ct, idx), s = sg * rdlane(st, idx);
    float xr = vr[0], xi = vi[0], yr = vr[1], yi = vi[1];
    vr[0] = c*xr + s*yi;  vi[0] = c*xi - s*yr;
    vr[1] = c*yr + s*xi;  vi[1] = c*yi - s*xr;
  }
}

// CRX control wire6 (h==1 waves), target lane wire T
template<int T>
__device__ __forceinline__ void crx_6l(float* vr, float* vi, Ctx& cx,
                                       float ct, float st, int idx, float sg) {
  if (cx.h) {
    float c = rdlane(ct, idx), s = sg * rdlane(st, idx);
    constexpr int LT = 1 << (5 - T);
#pragma unroll
    for (int r = 0; r < 2; ++r) {
      float pr = lane_partner<LT>(vr[r]);
      float pi = lane_partner<LT>(vi[r]);
      vr[r] = c*vr[r] + s*pi;
      vi[r] = c*vi[r] - s*pr;
    }
  }
}

// ---------------- sim14 layers (32 gates each) ----------------

__device__ __forceinline__ void sim14_fwd(float* vr, float* vi, Ctx& cx,
                                          float ct, float st, int off, float sg) {
  ry_lane<0>(vr,vi,cx,ct,st,off+0,sg); ry_lane<1>(vr,vi,cx,ct,st,off+1,sg);
  ry_lane<2>(vr,vi,cx,ct,st,off+2,sg); ry_lane<3>(vr,vi,cx,ct,st,off+3,sg);
  ry_lane<4>(vr,vi,cx,ct,st,off+4,sg); ry_lane<5>(vr,vi,cx,ct,st,off+5,sg);
  ry_wave6(vr,vi,cx,ct,st,off+6,sg);   ry_reg7(vr,vi,ct,st,off+7,sg);
  crx_7l<0>(vr,vi,cx,ct,st,off+8,sg);  crx_67(vr,vi,cx,ct,st,off+9,sg);
  crx_l6<5>(vr,vi,cx,ct,st,off+10,sg); crx_ll<4,5>(vr,vi,cx,ct,st,off+11,sg);
  crx_ll<3,4>(vr,vi,cx,ct,st,off+12,sg); crx_ll<2,3>(vr,vi,cx,ct,st,off+13,sg);
  crx_ll<1,2>(vr,vi,cx,ct,st,off+14,sg); crx_ll<0,1>(vr,vi,cx,ct,st,off+15,sg);
  ry_lane<0>(vr,vi,cx,ct,st,off+16,sg); ry_lane<1>(vr,vi,cx,ct,st,off+17,sg);
  ry_lane<2>(vr,vi,cx,ct,st,off+18,sg); ry_lane<3>(vr,vi,cx,ct,st,off+19,sg);
  ry_lane<4>(vr,vi,cx,ct,st,off+20,sg); ry_lane<5>(vr,vi,cx,ct,st,off+21,sg);
  ry_wave6(vr,vi,cx,ct,st,off+22,sg);   ry_reg7(vr,vi,ct,st,off+23,sg);
  crx_76(vr,vi,cx,ct,st,off+24,sg);     crx_l7<0>(vr,vi,cx,ct,st,off+25,sg);
  crx_ll<1,0>(vr,vi,cx,ct,st,off+26,sg); crx_ll<2,1>(vr,vi,cx,ct,st,off+27,sg);
  crx_ll<3,2>(vr,vi,cx,ct,st,off+28,sg); crx_ll<4,3>(vr,vi,cx,ct,st,off+29,sg);
  crx_ll<5,4>(vr,vi,cx,ct,st,off+30,sg); crx_6l<5>(vr,vi,cx,ct,st,off+31,sg);
}

__device__ __forceinline__ void sim14_adj(float* vr, float* vi, Ctx& cx,
                                          float ct, float st, int off) {
  const float sg = -1.f;
  crx_6l<5>(vr,vi,cx,ct,st,off+31,sg); crx_ll<5,4>(vr,vi,cx,ct,st,off+30,sg);
  crx_ll<4,3>(vr,vi,cx,ct,st,off+29,sg); crx_ll<3,2>(vr,vi,cx,ct,st,off+28,sg);
  crx_ll<2,1>(vr,vi,cx,ct,st,off+27,sg); crx_ll<1,0>(vr,vi,cx,ct,st,off+26,sg);
  crx_l7<0>(vr,vi,cx,ct,st,off+25,sg);   crx_76(vr,vi,cx,ct,st,off+24,sg);
  ry_reg7(vr,vi,ct,st,off+23,sg);        ry_wave6(vr,vi,cx,ct,st,off+22,sg);
  ry_lane<5>(vr,vi,cx,ct,st,off+21,sg); ry_lane<4>(vr,vi,cx,ct,st,off+20,sg);
  ry_lane<3>(vr,vi,cx,ct,st,off+19,sg); ry_lane<2>(vr,vi,cx,ct,st,off+18,sg);
  ry_lane<1>(vr,vi,cx,ct,st,off+17,sg); ry_lane<0>(vr,vi,cx,ct,st,off+16,sg);
  crx_ll<0,1>(vr,vi,cx,ct,st,off+15,sg); crx_ll<1,2>(vr,vi,cx,ct,st,off+14,sg);
  crx_ll<2,3>(vr,vi,cx,ct,st,off+13,sg); crx_ll<3,4>(vr,vi,cx,ct,st,off+12,sg);
  crx_ll<4,5>(vr,vi,cx,ct,st,off+11,sg); crx_l6<5>(vr,vi,cx,ct,st,off+10,sg);
  crx_67(vr,vi,cx,ct,st,off+9,sg);       crx_7l<0>(vr,vi,cx,ct,st,off+8,sg);
  ry_reg7(vr,vi,ct,st,off+7,sg);         ry_wave6(vr,vi,cx,ct,st,off+6,sg);
  ry_lane<5>(vr,vi,cx,ct,st,off+5,sg); ry_lane<4>(vr,vi,cx,ct,st,off+4,sg);
  ry_lane<3>(vr,vi,cx,ct,st,off+3,sg); ry_lane<2>(vr,vi,cx,ct,st,off+2,sg);
  ry_lane<1>(vr,vi,cx,ct,st,off+1,sg); ry_lane<0>(vr,vi,cx,ct,st,off+0,sg);
}

// ---------------- cooperative-row MLP layer (8 waves share rows) ----------------
// MODE: 0 = silu->yl, 1 = raw->yl, 2 = seltab ((float2*)yl)

template<int IN, int NP, int MODE>
__device__ __forceinline__ void mlp_layer(const float* __restrict__ W,
    const float* __restrict__ bias, const float* xl, float* yl,
    int rbase, int lane)
{
  const int sub = lane & 7;
  const int g   = lane >> 3;
#pragma unroll
  for (int p = 0; p < NP; ++p) {
    const int row = rbase + p * 8 + g;
    const float4* w4 = (const float4*)(W + row * IN) + sub;
    const float4* x4 = (const float4*)xl + sub;
    float acc = 0.f;
#pragma unroll
    for (int it = 0; it < IN / 32; ++it) {
      float4 w = w4[it * 8], e = x4[it * 8];
      acc += w.x*e.x + w.y*e.y + w.z*e.z + w.w*e.w;
    }
    acc = xor_sum<1>(acc);
    acc = xor_sum<2>(acc);
    acc = xor_sum<4>(acc);
    if (sub == 0) {
      float a = acc + bias[row];
      if constexpr (MODE == 0) {
        yl[row] = a / (1.f + __expf(-a));
      } else if constexpr (MODE == 1) {
        yl[row] = a;
      } else {
        float th = PI_F / (1.f + __expf(-a));   // theta/2 = pi * sigmoid(a)
        float sn, cn;
        __sincosf(th, &sn, &cn);
        ((float2*)yl)[row] = make_float2(cn, sn);
      }
    }
  }
}

// ---------------- main kernel: 512 threads = 8 waves, one batch elem/block ----------------

__global__ __launch_bounds__(512) void qsvt_kernel(
    const float* __restrict__ z_t, const float* __restrict__ t,
    const float* __restrict__ te_w1, const float* __restrict__ te_b1,
    const float* __restrict__ te_w2, const float* __restrict__ te_b2,
    const float* __restrict__ ip_w1, const float* __restrict__ ip_b1,
    const float* __restrict__ ip_w2, const float* __restrict__ ip_b2,
    const float* __restrict__ prep_p, const float* __restrict__ sig,
    const float* __restrict__ qff, const float* __restrict__ A_obs,
    const float* __restrict__ B_obs, const float* __restrict__ D_obs,
    const float* __restrict__ head_w, const float* __restrict__ head_b,
    float* __restrict__ out)
{
  __shared__ __align__(16) float emb[128];
  __shared__ __align__(16) float y1[128];
  __shared__ __align__(16) float hbuf[256];
  __shared__ __align__(16) float h1[256];
  __shared__ __align__(16) float2 seltab[256];   // [s*64+g] -> (cos(th/2), sin(th/2))
  __shared__ __align__(16) float2 qtab[32];
  __shared__ __align__(16) float4 xw[2 * 8 * 64]; // wave-pair exchange (double-buffered)
  __shared__ __align__(16) float2 xanc[128 * 9];  // ancilla exchange, region stride 9
  __shared__ __align__(16) float dumpR[4][256];
  __shared__ __align__(16) float dumpI[4][256];
  __shared__ float redbuf[NOBS][4];
  __shared__ float hdc[NOBS][3], hxc[NOBS][6], hyc[NOBS][6];
  __shared__ __align__(16) float shw[128 * NOBS];
  __shared__ __align__(16) float shb[128];

  const int tid  = threadIdx.x;
  const int lane = tid & 63;
  const int wv   = tid >> 6;   // 0..7
  const int s    = wv & 3;     // ancilla value
  const int h    = wv >> 2;    // wire-6 value
  const int b    = blockIdx.x;

  // ===== Phase A: MLP (cooperative rows, 8 waves) =====
  if (tid < 128) {
    int j = tid & 63;
    float fr = __expf(-9.210340371976184f * (float)j / 64.f);  // exp(-ln(1e4)*j/64)
    float arg = t[b] * fr;
    float sn, cn;
    __sincosf(arg, &sn, &cn);
    emb[tid] = (tid < 64) ? cn : sn;
  } else if (tid < 160) {
    int j = tid - 128;
    float sn, cn;
    __sincosf(0.5f * qff[j], &sn, &cn);
    qtab[j] = make_float2(cn, sn);
  }
  __syncthreads();

  mlp_layer<128, 2, 0>(te_w1, te_b1, emb, y1, wv * 16, lane);
  if (tid < 128) hbuf[tid] = z_t[b * 128 + tid];
  __syncthreads();

  mlp_layer<128, 2, 1>(te_w2, te_b2, y1, hbuf + 128, wv * 16, lane);
  __syncthreads();

  mlp_layer<256, 4, 0>(ip_w1, ip_b1, hbuf, h1, wv * 32, lane);
  __syncthreads();

  mlp_layer<256, 4, 2>(ip_w2, ip_b2, h1, (float*)seltab, wv * 32, lane);

  // prefetch observable + head coefficients into LDS (off the tail path)
  if (tid < NOBS * 6)      { hxc[tid/6][tid%6] = A_obs[tid]; hyc[tid/6][tid%6] = B_obs[tid]; }
  else if (tid >= 64 && tid < 64 + NOBS*3) { int q = tid - 64; hdc[q/3][q%3] = 2.f * D_obs[(q/3)*4 + (q%3) + 1]; }
#pragma unroll
  for (int i = tid; i < 128*NOBS; i += 512) shw[i] = head_w[i];
  if (tid < 128) shb[tid] = head_b[tid];

  // ===== Phase B: per-thread 4x4 ancilla matrices (registers) =====
  float2 Ga[2][2][2], Gb[2][2][2];
#pragma unroll
  for (int ly = 0; ly < 2; ++ly) {
#pragma unroll
    for (int qi = 0; qi < 2; ++qi) {
      float y = prep_p[ly*4 + qi*2 + 0], z = prep_p[ly*4 + qi*2 + 1];
      float cy, sy, cz, sz;
      __sincosf(0.5f*y, &sy, &cy);
      __sincosf(0.5f*z, &sz, &cz);
      float2 g00 = make_float2( cy*cz, -cy*sz);
      float2 g01 = make_float2(-sy*cz,  sy*sz);
      float2 g10 = make_float2( sy*cz,  sy*sz);
      float2 g11 = make_float2( cy*cz,  cy*sz);
      if (qi == 0) { Ga[ly][0][0]=g00; Ga[ly][0][1]=g01; Ga[ly][1][0]=g10; Ga[ly][1][1]=g11; }
      else         { Gb[ly][0][0]=g00; Gb[ly][0][1]=g01; Gb[ly][1][0]=g10; Gb[ly][1][1]=g11; }
    }
  }
  float2 M[2][4][4];
#pragma unroll
  for (int ly = 0; ly < 2; ++ly) {
    float2 T[4][4];
#pragma unroll
    for (int i = 0; i < 4; ++i)
#pragma unroll
      for (int j = 0; j < 4; ++j)
        T[i][j] = cmul(Ga[ly][i>>1][j>>1], Gb[ly][i&1][j&1]);
#pragma unroll
    for (int j = 0; j < 4; ++j) {
      M[ly][0][j] = T[0][j]; M[ly][1][j] = T[1][j];
      M[ly][2][j] = T[3][j]; M[ly][3][j] = T[2][j];
    }
  }
  float2 U[4][4];
#pragma unroll
  for (int i = 0; i < 4; ++i)
#pragma unroll
    for (int j = 0; j < 4; ++j) {
      float2 acc = make_float2(0.f, 0.f);
#pragma unroll
      for (int kk = 0; kk < 4; ++kk) acc = cadd(acc, cmul(M[1][i][kk], M[0][kk][j]));
      U[i][j] = acc;
    }
  float2 Urow[4], Ucol[4];
#pragma unroll
  for (int j = 0; j < 4; ++j) {
    Urow[j] = s==0 ? U[0][j] : s==1 ? U[1][j] : s==2 ? U[2][j] : U[3][j];
    Ucol[j] = s==0 ? U[j][0] : s==1 ? U[j][1] : s==2 ? U[j][2] : U[j][3];
  }
  float sg0 = sig[0], sg1 = sig[1], sg2 = sig[2], sg3 = sig[3];
  float c1, s1v, c2, s2v, c3, s3v;
  __sincosf(sg1, &s1v, &c1);
  __sincosf(sg2, &s2v, &c2);
  __sincosf(sg3, &s3v, &c3);
  float2 R1[4], R2[4], RF[4];
  {
    float s3s = (s == 0) ? s3v : -s3v;
    float2 d3 = make_float2(c3, s3s);
#pragma unroll
    for (int sp = 0; sp < 4; ++sp) {
      float2 a1 = make_float2(0.f, 0.f), a2 = make_float2(0.f, 0.f);
#pragma unroll
      for (int j = 0; j < 4; ++j) {
        float2 uspj = sp==0 ? U[0][j] : sp==1 ? U[1][j] : sp==2 ? U[2][j] : U[3][j];
        float2 tt = cmulc(Urow[j], uspj);            // U[s][j] * conj(U[sp][j])
        float sj = (j == 0) ? 1.f : -1.f;
        a1 = cadd(a1, cmul(tt, make_float2(c1, sj*s1v)));
        a2 = cadd(a2, cmul(tt, make_float2(c2, sj*s2v)));
      }
      R1[sp] = a1; R2[sp] = a2;
      RF[sp] = cmul(d3, make_float2(Ucol[sp].x, -Ucol[sp].y));  // D3[s]*conj(U[sp][s])
    }
  }
  __syncthreads();  // seltab/qtab/coefs visible to all waves

  // pull this wave's angle tables into registers (lane g <-> gate g)
  float2 mycs = seltab[(s << 6) | lane];
  float selc = mycs.x, sels = mycs.y;
  float2 myq = qtab[lane & 31];
  float qc = myq.x, qs = myq.y;

  Ctx cx; cx.xw = xw; cx.pp = 0; cx.wv = wv; cx.lane = lane; cx.h = h;

  // ===== Phase C: circuit. init = U * D0 * |0..0> : only m=0 (lane0,h0,r0) =====
  float vr[2], vi[2];
  vr[0] = 0.f; vr[1] = 0.f; vi[0] = 0.f; vi[1] = 0.f;
  if (lane == 0 && h == 0) {
    float s0n, c0n;
    __sincosf(sg0, &s0n, &c0n);
    float2 a0 = cmul(Urow[0], make_float2(c0n, s0n));
    vr[0] = a0.x; vi[0] = a0.y;
  }

  const int ancbase = (h * 64 + lane) * 9;

  // select_0 (fwd)
  sim14_fwd(vr, vi, cx, selc, sels, 0, 1.f);
  sim14_fwd(vr, vi, cx, selc, sels, 32, 1.f);
  // exchange X1 (mix ancilla s among 4 waves of same h)
  {
#pragma unroll
    for (int r = 0; r < 2; ++r) xanc[ancbase + r*4 + s] = make_float2(vr[r], vi[r]);
    __syncthreads();
#pragma unroll
    for (int r = 0; r < 2; ++r) {
      const float2* p = &xanc[ancbase + r*4];
      float2 o = cmul(R1[0], p[0]);
      o = cadd(o, cmul(R1[1], p[1]));
      o = cadd(o, cmul(R1[2], p[2]));
      o = cadd(o, cmul(R1[3], p[3]));
      vr[r] = o.x; vi[r] = o.y;
    }
    __syncthreads();
  }
  // select_1 (adjoint)
  sim14_adj(vr, vi, cx, selc, sels, 32);
  sim14_adj(vr, vi, cx, selc, sels, 0);
  // exchange X2
  {
#pragma unroll
    for (int r = 0; r < 2; ++r) xanc[ancbase + r*4 + s] = make_float2(vr[r], vi[r]);
    __syncthreads();
#pragma unroll
    for (int r = 0; r < 2; ++r) {
      const float2* p = &xanc[ancbase + r*4];
      float2 o = cmul(R2[0], p[0]);
      o = cadd(o, cmul(R2[1], p[1]));
      o = cadd(o, cmul(R2[2], p[2]));
      o = cadd(o, cmul(R2[3], p[3]));
      vr[r] = o.x; vi[r] = o.y;
    }
    __syncthreads();
  }
  // select_2 (fwd)
  sim14_fwd(vr, vi, cx, selc, sels, 0, 1.f);
  sim14_fwd(vr, vi, cx, selc, sels, 32, 1.f);
  // exchange F = D3 U^
  {
#pragma unroll
    for (int r = 0; r < 2; ++r) xanc[ancbase + r*4 + s] = make_float2(vr[r], vi[r]);
    __syncthreads();
#pragma unroll
    for (int r = 0; r < 2; ++r) {
      const float2* p = &xanc[ancbase + r*4];
      float2 o = cmul(RF[0], p[0]);
      o = cadd(o, cmul(RF[1], p[1]));
      o = cadd(o, cmul(RF[2], p[2]));
      o = cadd(o, cmul(RF[3], p[3]));
      vr[r] = o.x; vi[r] = o.y;
    }
    __syncthreads();
  }
  // final sim14 layer with qff angles (uniform across s)
  sim14_fwd(vr, vi, cx, qc, qs, 0, 1.f);

  // ===== Phase D: dump state, observables =====
  // m = (lane<<2)|(h<<1)|r ; write (r=0,1) as one float2
  *(float2*)&dumpR[s][(lane << 2) | (h << 1)] = make_float2(vr[0], vr[1]);
  *(float2*)&dumpI[s][(lane << 2) | (h << 1)] = make_float2(vi[0], vi[1]);
  __syncthreads();  // obs reads cross h

  // h=0 waves: w 0..3 ; h=1 waves: w 4..6
  const int w0 = h ? 4 : 0, w1 = h ? NOBS : 4;
  for (int w = w0; w < w1; ++w) {
    const int pb = 6 - w;  // wires (w, w+1) -> bits (7-w, 6-w) of m
    int g = lane;
    int ib = ((g >> pb) << (pb + 2)) | (g & ((1 << pb) - 1));
    float xr[4], xi[4];
#pragma unroll
    for (int i = 0; i < 4; ++i) { xr[i] = dumpR[s][ib + (i << pb)]; xi[i] = dumpI[s][ib + (i << pb)]; }
    float a = hdc[w][0] * (xr[0]*xr[0] + xi[0]*xi[0])
            + hdc[w][1] * (xr[1]*xr[1] + xi[1]*xi[1])
            + hdc[w][2] * (xr[2]*xr[2] + xi[2]*xi[2]);
    const int oi[6] = {1, 2, 2, 3, 3, 3};
    const int oj[6] = {0, 0, 1, 0, 1, 2};
#pragma unroll
    for (int k2 = 0; k2 < 6; ++k2) {
      int i = oi[k2], j = oj[k2];
      float rr = xr[i]*xr[j] + xi[i]*xi[j];   // Re(conj(v_i) v_j)
      float ii = xr[i]*xi[j] - xi[i]*xr[j];   // Im(conj(v_i) v_j)
      a += 2.f * (hxc[w][k2]*rr - hyc[w][k2]*ii);
    }
    a = xor_sum<32>(a);
    a = xor_sum<16>(a);
    a = xor_sum<8>(a);
    a = xor_sum<4>(a);
    a = xor_sum<2>(a);
    a = xor_sum<1>(a);
    if (lane == 0) redbuf[w][s] = a;
  }
  __syncthreads();

  // ===== Phase E: head =====
  if (tid < 128) {
    float acc = shb[tid];
#pragma unroll
    for (int w = 0; w < NOBS; ++w) {
      float ev = redbuf[w][0] + redbuf[w][1] + redbuf[w][2] + redbuf[w][3];
      acc += ev * shw[tid*NOBS + w];
    }
    out[b * 128 + tid] = acc;
  }
}

extern "C" void kernel_launch(void* const* d_in, const int* in_sizes, int n_in,
                              void* d_out, int out_size, void* d_ws, size_t ws_size,
                              hipStream_t stream) {
  (void)n_in; (void)out_size; (void)d_ws; (void)ws_size;
  const float* z_t    = (const float*)d_in[0];
  const float* t      = (const float*)d_in[1];
  const float* te_w1  = (const float*)d_in[2];
  const float* te_b1  = (const float*)d_in[3];
  const float* te_w2  = (const float*)d_in[4];
  const float* te_b2  = (const float*)d_in[5];
  const float* ip_w1  = (const float*)d_in[6];
  const float* ip_b1  = (const float*)d_in[7];
  const float* ip_w2  = (const float*)d_in[8];
  const float* ip_b2  = (const float*)d_in[9];
  const float* prep_p = (const float*)d_in[10];
  const float* sig    = (const float*)d_in[11];
  const float* qff    = (const float*)d_in[12];
  const float* A_obs  = (const float*)d_in[13];
  const float* B_obs  = (const float*)d_in[14];
  const float* D_obs  = (const float*)d_in[15];
  const float* head_w = (const float*)d_in[16];
  const float* head_b = (const float*)d_in[17];
  float* out = (float*)d_out;

  int B = in_sizes[1];  // t is (B,)
  qsvt_kernel<<<B, 512, 0, stream>>>(
      z_t, t, te_w1, te_b1, te_w2, te_b2, ip_w1, ip_b1, ip_w2, ip_b2,
      prep_p, sig, qff, A_obs, B_obs, D_obs, head_w, head_b, out);
}